// Round 5
// baseline (350.159 us; speedup 1.0000x reference)
//
#include <hip/hip_runtime.h>
#include <cmath>

// ---- problem constants ----
#define DIMC   256
#define L_WIN  1023        // (131072-256)/128 + 1
#define M_VALID 4092       // 4*1023 tokens
#define M_PAD  4096
#define DI     1024        // D_INNER
#define TLEN   131072
#define SEG    64          // scan segment length
#define NSEG   16          // 16*64 = 1024 >= 1023
#define CBT    8           // tokens per conv_xproj block

typedef __bf16 bf16x8 __attribute__((ext_vector_type(8)));
typedef __bf16 bf16x4 __attribute__((ext_vector_type(4)));
typedef float  f32x4  __attribute__((ext_vector_type(4)));

#define LOG2E 1.4426950408889634f

__device__ __forceinline__ float sigmoidf_(float x){ return 1.f/(1.f + __expf(-x)); }
__device__ __forceinline__ float softplusf_(float v){ return fmaxf(v,0.f) + log1pf(__expf(-fabsf(v))); }

// DPP rotate-add: pure-VALU cross-lane sum step (no LDS traffic)
template<int CTRL>
__device__ __forceinline__ float dpp_add(float x){
  int v = __builtin_amdgcn_update_dpp(0, __builtin_bit_cast(int, x), CTRL, 0xF, 0xF, true);
  return x + __builtin_bit_cast(float, v);
}

// ---------------- init: frame (blocks 0..4095) + weight bf16 convert (blocks 4096+) ----------------
__global__ __launch_bounds__(256) void init_kernel(const float* __restrict__ x, float* __restrict__ res,
    const float* __restrict__ a, __bf16* __restrict__ da, int na,
    const float* __restrict__ b, __bf16* __restrict__ db, int nb,
    const float* __restrict__ c, __bf16* __restrict__ dc, int nc)
{
  if (blockIdx.x < M_PAD){
    int m = blockIdx.x, j = threadIdx.x;
    float v = 0.f;
    if (m < M_VALID){
      int bb = m / L_WIN, l = m - bb*L_WIN;
      v = x[(size_t)bb*TLEN + l*128 + j];
    }
    res[(size_t)m*DIMC + j] = v;
    return;
  }
  int nblk = gridDim.x - M_PAD;
  int stride = nblk*256;
  int base = (blockIdx.x - M_PAD)*256 + threadIdx.x;
  for (int i = base; i < na; i += stride) da[i] = (__bf16)a[i];
  for (int i = base; i < nb; i += stride) db[i] = (__bf16)b[i];
  for (int i = base; i < nc; i += stride) dc[i] = (__bf16)c[i];
}

// ---------------- rmsnorm row of 256 -> bf16 (kept separate: fusing into the GEMM
// recomputes row sums 16x per tile and regressed 27 us — r2 post-mortem) ----------------
__global__ __launch_bounds__(256) void rms_kernel(const float* __restrict__ src, __bf16* __restrict__ dst,
                                                  const float* __restrict__ w){
  int m = blockIdx.x, j = threadIdx.x;
  float v = (m < M_VALID) ? src[(size_t)m*DIMC + j] : 0.f;
  float s = v*v;
  #pragma unroll
  for (int off = 32; off; off >>= 1) s += __shfl_down(s, off);
  __shared__ float ls[4];
  if ((threadIdx.x & 63) == 0) ls[threadIdx.x >> 6] = s;
  __syncthreads();
  float tot = ls[0] + ls[1] + ls[2] + ls[3];
  float scale = rsqrtf(tot * (1.f/DIMC) + 1e-5f);
  dst[(size_t)m*DIMC + j] = (__bf16)(v * scale * w[j]);
}

// ======== LDS-tiled bf16 MFMA GEMM: C[M x N] = A[M x K] * B[N x K]^T (+addsrc) ========
// NOTE: C/addsrc NOT __restrict__ — out_proj call is in-place (C==addsrc).
template<int WM, int WN, typename OutT>
__global__ __launch_bounds__(256) void gemm_tiled_kernel(const __bf16* __restrict__ A, const __bf16* __restrict__ B,
    OutT* C, const float* addsrc, int K, int ldc)
{
  constexpr int BM  = 32*WM;
  constexpr int BN  = 32*WN;
  constexpr int LDK = 72;
  __shared__ __bf16 As[BM*LDK];
  __shared__ __bf16 Bs[BN*LDK];
  int tid  = threadIdx.x;
  int lane = tid & 63, wv = tid >> 6;
  int row  = lane & 15, kq = lane >> 4;
  int m0 = blockIdx.x*BM, n0 = blockIdx.y*BN;
  int wmo = (wv >> 1)*(16*WM);
  int wno = (wv &  1)*(16*WN);
  f32x4 acc[WM][WN] = {};
  for (int kt = 0; kt < K; kt += 64){
    __syncthreads();
    #pragma unroll
    for (int r = 0; r < BM/32; ++r){
      int seg = r*256 + tid;
      int rw = seg >> 3, sb = seg & 7;
      *(bf16x8*)(As + rw*LDK + sb*8) = *(const bf16x8*)(A + (size_t)(m0 + rw)*K + kt + sb*8);
    }
    #pragma unroll
    for (int r = 0; r < BN/32; ++r){
      int seg = r*256 + tid;
      int rw = seg >> 3, sb = seg & 7;
      *(bf16x8*)(Bs + rw*LDK + sb*8) = *(const bf16x8*)(B + (size_t)(n0 + rw)*K + kt + sb*8);
    }
    __syncthreads();
    #pragma unroll
    for (int ks = 0; ks < 2; ++ks){
      bf16x8 af[WM], bfr[WN];
      #pragma unroll
      for (int i = 0; i < WM; ++i) af[i]  = *(const bf16x8*)(As + (wmo + i*16 + row)*LDK + ks*32 + kq*8);
      #pragma unroll
      for (int j = 0; j < WN; ++j) bfr[j] = *(const bf16x8*)(Bs + (wno + j*16 + row)*LDK + ks*32 + kq*8);
      #pragma unroll
      for (int i = 0; i < WM; ++i){
        #pragma unroll
        for (int j = 0; j < WN; ++j)
          acc[i][j] = __builtin_amdgcn_mfma_f32_16x16x32_bf16(af[i], bfr[j], acc[i][j], 0, 0, 0);
      }
    }
  }
  #pragma unroll
  for (int i = 0; i < WM; ++i){
    int cm = m0 + wmo + i*16 + kq*4;
    #pragma unroll
    for (int j = 0; j < WN; ++j){
      int cn = n0 + wno + j*16 + row;
      #pragma unroll
      for (int ii = 0; ii < 4; ++ii){
        size_t idx = (size_t)(cm + ii)*ldc + cn;
        float v = acc[i][j][ii];
        if (addsrc) v += addsrc[idx];
        C[idx] = (OutT)v;
      }
    }
  }
}

// ======== fused conv4+SiLU -> xproj MFMA (K-split) -> dt_proj+softplus ========
__global__ __launch_bounds__(256) void conv_xproj_dt_kernel(
  const __bf16* __restrict__ xz16, const float* __restrict__ cw, const float* __restrict__ cb,
  const __bf16* __restrict__ wxp, const float* __restrict__ dtw, const float* __restrict__ dtb,
  __bf16* __restrict__ u16, float* __restrict__ xdbl, __bf16* __restrict__ delta16)
{
  __shared__ __bf16 su[16][1032];     // rows 0..CBT-1 valid; +8 pad
  __shared__ float  sdt[CBT][17];
  __shared__ f32x4  spart[4][3][64];  // [kwave][tile][lane] partial xproj sums
  int tid = threadIdx.x;
  int m0 = blockIdx.x * CBT;
  // ---- phase A: causal depthwise conv4 + bias + SiLU (rolling 4-row register window) ----
  {
    int d = tid * 4;
    float w[4][4], bias[4];
    #pragma unroll
    for (int c = 0; c < 4; ++c){
      #pragma unroll
      for (int j = 0; j < 4; ++j) w[c][j] = cw[(d + c)*4 + j];
      bias[c] = cb[d + c];
    }
    bf16x4 zero4; zero4[0] = (__bf16)0.f; zero4[1] = (__bf16)0.f; zero4[2] = (__bf16)0.f; zero4[3] = (__bf16)0.f;
    bf16x4 rm3 = (m0 >= 3) ? *(const bf16x4*)(xz16 + (size_t)(m0-3)*2048 + d) : zero4;
    bf16x4 rm2 = (m0 >= 2) ? *(const bf16x4*)(xz16 + (size_t)(m0-2)*2048 + d) : zero4;
    bf16x4 rm1 = (m0 >= 1) ? *(const bf16x4*)(xz16 + (size_t)(m0-1)*2048 + d) : zero4;
    for (int ti = 0; ti < CBT; ++ti){
      int m = m0 + ti;
      bf16x4 cur = *(const bf16x4*)(xz16 + (size_t)m*2048 + d);
      float acc[4] = {0.f, 0.f, 0.f, 0.f};
      if (m < M_VALID){
        int b = m / L_WIN;
        int l = m - b*L_WIN;
        #pragma unroll
        for (int c = 0; c < 4; ++c) acc[c] = fmaf((float)cur[c], w[c][3], bias[c]);
        if (l >= 1){
          #pragma unroll
          for (int c = 0; c < 4; ++c) acc[c] = fmaf((float)rm1[c], w[c][2], acc[c]);
        }
        if (l >= 2){
          #pragma unroll
          for (int c = 0; c < 4; ++c) acc[c] = fmaf((float)rm2[c], w[c][1], acc[c]);
        }
        if (l >= 3){
          #pragma unroll
          for (int c = 0; c < 4; ++c) acc[c] = fmaf((float)rm3[c], w[c][0], acc[c]);
        }
        #pragma unroll
        for (int c = 0; c < 4; ++c) acc[c] = acc[c] * sigmoidf_(acc[c]);
      }
      bf16x4 o;
      #pragma unroll
      for (int c = 0; c < 4; ++c) o[c] = (__bf16)acc[c];
      *(bf16x4*)(u16 + (size_t)m*DI + d) = o;
      *(bf16x4*)(&su[ti][d]) = o;
      rm3 = rm2; rm2 = rm1; rm1 = cur;
    }
  }
  __syncthreads();
  // ---- phase B: xproj, CBT tokens x 48 outputs, K=1024 split across 4 waves ----
  {
    int lane = tid & 63, wv = tid >> 6;
    int row = lane & 15, kq = lane >> 4;
    int kbase = wv * 256;
    f32x4 acc0 = {0,0,0,0}, acc1 = {0,0,0,0}, acc2 = {0,0,0,0};
    const __bf16* B0 = wxp + (size_t)(row)*1024      + kbase + kq*8;
    const __bf16* B1 = wxp + (size_t)(16 + row)*1024 + kbase + kq*8;
    const __bf16* B2 = wxp + (size_t)(32 + row)*1024 + kbase + kq*8;
    #pragma unroll
    for (int k = 0; k < 256; k += 32){
      bf16x8 a = *(const bf16x8*)(&su[row][kbase + k + kq*8]);
      acc0 = __builtin_amdgcn_mfma_f32_16x16x32_bf16(a, *(const bf16x8*)(B0 + k), acc0, 0, 0, 0);
      acc1 = __builtin_amdgcn_mfma_f32_16x16x32_bf16(a, *(const bf16x8*)(B1 + k), acc1, 0, 0, 0);
      acc2 = __builtin_amdgcn_mfma_f32_16x16x32_bf16(a, *(const bf16x8*)(B2 + k), acc2, 0, 0, 0);
    }
    spart[wv][0][lane] = acc0;
    spart[wv][1][lane] = acc1;
    spart[wv][2][lane] = acc2;
  }
  __syncthreads();
  // ---- reduce partials, write xdbl + sdt (only valid tokens) ----
  if (tid < 192){
    int tno = tid >> 6, lane = tid & 63;
    int row = lane & 15, kq = lane >> 4;
    f32x4 sum = spart[0][tno][lane];
    sum += spart[1][tno][lane];
    sum += spart[2][tno][lane];
    sum += spart[3][tno][lane];
    #pragma unroll
    for (int i = 0; i < 4; ++i){
      int tok = kq*4 + i;
      if (tok < CBT){
        xdbl[(size_t)(m0 + tok)*48 + tno*16 + row] = sum[i];
        if (tno == 0) sdt[tok][row] = sum[i];
      }
    }
  }
  __syncthreads();
  // ---- phase C: dt_proj (K=16) + softplus -> delta16 ----
  {
    int d0 = tid * 4;
    float w[4][16], bias[4];
    #pragma unroll
    for (int c = 0; c < 4; ++c){
      #pragma unroll
      for (int q = 0; q < 16; ++q) w[c][q] = dtw[(d0 + c)*16 + q];
      bias[c] = dtb[d0 + c];
    }
    for (int t = 0; t < CBT; ++t){
      float acc[4] = {bias[0], bias[1], bias[2], bias[3]};
      #pragma unroll
      for (int r = 0; r < 16; ++r){
        float dv = sdt[t][r];
        #pragma unroll
        for (int c = 0; c < 4; ++c) acc[c] = fmaf(dv, w[c][r], acc[c]);
      }
      bf16x4 o;
      #pragma unroll
      for (int c = 0; c < 4; ++c) o[c] = (__bf16)softplusf_(acc[c]);
      *(bf16x4*)(delta16 + (size_t)(m0 + t)*DI + d0) = o;
    }
  }
}

// ================= chunked two-phase selective scan =================
__global__ __launch_bounds__(256) void scan_part1_kernel(
  const __bf16* __restrict__ u16, const __bf16* __restrict__ delta16,
  const float* __restrict__ xdbl, const float* __restrict__ Alog, float2* __restrict__ Pq)
{
  int bid = blockIdx.x;
  int s = bid & 15, dtile = (bid >> 4) & 63, b = bid >> 10;
  int d0 = dtile << 4;
  int tid = threadIdx.x;
  int c = tid >> 4, n = tid & 15;
  float A2 = -__expf(Alog[(d0 + c)*16 + n]) * LOG2E;   // exp(dlt*A) = exp2(dlt*A2)
  __shared__ float2 sdd[16][SEG+2];   // (dlt, dlt*u)
  __shared__ float  sB [SEG][17];
  int t0 = s*SEG;
  int nt = L_WIN - t0; if (nt > SEG) nt = SEG;
  size_t base_m = (size_t)b*L_WIN + t0;
  for (int i2 = tid; i2 < 16*SEG; i2 += 256){
    int tt = i2 >> 4, dd = i2 & 15;
    float dlt = 0.f, du = 0.f, Bv = 0.f;
    if (tt < nt){
      size_t m = base_m + tt;
      dlt = (float)delta16[m*DI + d0 + dd];
      du  = dlt * (float)u16[m*DI + d0 + dd];
      Bv  = xdbl[m*48 + 16 + dd];
    }
    sdd[dd][tt] = make_float2(dlt, du);
    sB[tt][dd]  = Bv;
  }
  __syncthreads();
  float h = 0.f, sd = 0.f;
  #pragma unroll 8
  for (int t = 0; t < SEG; ++t){
    float2 dd2 = sdd[c][t];
    float dA = exp2f(dd2.x * A2);
    h = fmaf(dA, h, dd2.y * sB[t][n]);
    sd += dd2.x;                        // P = exp2(A2 * sum(dlt)): one exp2 at end
  }
  float P = exp2f(sd * A2);
  Pq[(((size_t)b*NSEG + s) << 14) + (dtile << 8) + tid] = make_float2(P, h);
}

// r5: r3 structure (2 barriers, in-register butterfly) but butterfly cut 4->2
// DPP steps: xor1+xor2 give per-quad (4-state) partial sums; one lane/quad
// writes sy4[t][c*4+q] (16 consecutive banks per wave, conflict-free); the
// existing global epilogue absorbs the final 3 adds via an aligned f32x4 read.
// r4 lesson (ledger): LDS-round-trip reduction lost to occupancy+conflicts;
// keep the reduce in-register, keep LDS small, keep 2 barriers.
__global__ __launch_bounds__(256) void scan_part2_kernel(
  const __bf16* __restrict__ u16, const __bf16* __restrict__ delta16,
  const float* __restrict__ xdbl, const __bf16* __restrict__ xz16,
  const float* __restrict__ Alog, const float* __restrict__ Dp,
  const float2* __restrict__ Pq, __bf16* __restrict__ y16)
{
  int bid = blockIdx.x;
  int s = bid & 15, dtile = (bid >> 4) & 63, b = bid >> 10;
  int d0 = dtile << 4;
  int tid = threadIdx.x;
  int c = tid >> 4, n = tid & 15;
  float A2 = -__expf(Alog[(d0 + c)*16 + n]) * LOG2E;
  __shared__ float2 sdd[16][SEG+2];   // (dlt, u)            8.4 KB
  __shared__ float2 sBC[SEG][17];     // (B_n, C_n)          8.7 KB
  __shared__ float  sy4[SEG*64];      // [t][c*4+q] quad partial sums (16 KB)
  __shared__ float  sD[16];
  if (tid < 16) sD[tid] = Dp[d0 + tid];
  int t0 = s*SEG;
  int nt = L_WIN - t0; if (nt > SEG) nt = SEG;
  size_t base_m = (size_t)b*L_WIN + t0;
  // ---- staging first: HBM loads issue before the serial Pq-prefix chain ----
  for (int i2 = tid; i2 < 16*SEG; i2 += 256){
    int tt = i2 >> 4, dd = i2 & 15;
    float dlt = 0.f, uu = 0.f, Bv = 0.f, Cv = 0.f;
    if (tt < nt){
      size_t m = base_m + tt;
      dlt = (float)delta16[m*DI + d0 + dd];
      uu  = (float)u16[m*DI + d0 + dd];
      Bv  = xdbl[m*48 + 16 + dd];
      Cv  = xdbl[m*48 + 32 + dd];
    }
    sdd[dd][tt] = make_float2(dlt, uu);
    sBC[tt][dd] = make_float2(Bv, Cv);
  }
  // ---- prefix over earlier segments' (P,q): h_start for this block ----
  float h = 0.f;
  for (int sp = 0; sp < s; ++sp){
    float2 pq = Pq[(((size_t)b*NSEG + sp) << 14) + (dtile << 8) + tid];
    h = fmaf(pq.x, h, pq.y);
  }
  __syncthreads();
  bool wl = ((n & 3) == 0);
  int widx = c*4 + (n >> 2);
  #pragma unroll 8
  for (int t = 0; t < SEG; ++t){
    float2 dd2 = sdd[c][t];
    float dA = exp2f(dd2.x * A2);
    float2 bc = sBC[t][n];
    h = fmaf(dA, h, dd2.x * dd2.y * bc.x);
    float pp = h * bc.y;
    pp = dpp_add<0xB1>(pp);    // + lane^1
    pp = dpp_add<0x4E>(pp);    // + lane^2 -> sum over 4-state quad
    if (wl) sy4[t*64 + widx] = pp;
  }
  __syncthreads();
  for (int i2 = tid; i2 < 16*nt; i2 += 256){
    int tt = i2 >> 4, dd = i2 & 15;
    size_t m = base_m + tt;
    f32x4 q4 = *(const f32x4*)&sy4[tt*64 + dd*4];
    float uv = sdd[dd][tt].y;
    float zv = (float)xz16[m*2048 + 1024 + d0 + dd];
    float yv = (((q4[0] + q4[1]) + (q4[2] + q4[3])) + uv * sD[dd]) * (zv * sigmoidf_(zv));
    y16[m*DI + d0 + dd] = (__bf16)yv;
  }
}

// ---------------- overlap-add fold + passthrough ----------------
__global__ __launch_bounds__(256) void fold_kernel(const float* __restrict__ x, const float* __restrict__ r,
                                                   float* __restrict__ out){
  int i = blockIdx.x*256 + threadIdx.x;
  int b = i >> 17;
  int t = i & (TLEN - 1);
  float acc = x[i];
  int l1 = t >> 7;
  int j  = t & 127;
  if (l1 < L_WIN) acc += r[((size_t)b*L_WIN + l1)*DIMC + j] * ((float)j * (1.f/127.f));
  if (l1 >= 1)    acc += r[((size_t)b*L_WIN + l1 - 1)*DIMC + j + 128] * ((float)(127 - j) * (1.f/127.f));
  out[i] = acc;
}

extern "C" void kernel_launch(void* const* d_in, const int* in_sizes, int n_in,
                              void* d_out, int out_size, void* d_ws, size_t ws_size,
                              hipStream_t stream)
{
  (void)in_sizes; (void)n_in; (void)out_size; (void)ws_size;
  const float* x      = (const float*)d_in[0];
  const float* in_w   = (const float*)d_in[1];
  const float* conv_w = (const float*)d_in[2];
  const float* conv_b = (const float*)d_in[3];
  const float* xp_w   = (const float*)d_in[4];
  const float* dt_w   = (const float*)d_in[5];
  const float* dt_b   = (const float*)d_in[6];
  const float* A_log  = (const float*)d_in[7];
  const float* Dp     = (const float*)d_in[8];
  const float* out_w  = (const float*)d_in[9];
  const float* norm_w = (const float*)d_in[10];
  float* out = (float*)d_out;

  // workspace layout (~56 MB; ws is 256 MiB)
  char* p = (char*)d_ws;
  auto alloc = [&](size_t bytes)->void*{ void* r = (void*)p; p += (bytes + 255) & ~(size_t)255; return r; };
  float*  res    = (float*) alloc((size_t)M_PAD*DIMC*4);        // 4 MB
  __bf16* hn16   = (__bf16*)alloc((size_t)M_PAD*DIMC*2);        // 2 MB
  __bf16* xz16   = (__bf16*)alloc((size_t)M_PAD*2048*2);        // 16 MB
  __bf16* u16    = (__bf16*)alloc((size_t)M_PAD*DI*2);          // 8 MB
  float*  xdbl   = (float*) alloc((size_t)M_PAD*48*4);          // 0.75 MB
  __bf16* delta16= (__bf16*)alloc((size_t)M_PAD*DI*2);          // 8 MB
  __bf16* y16    = (__bf16*)alloc((size_t)M_PAD*DI*2);          // 8 MB
  float2* Pq     = (float2*)alloc((size_t)4*NSEG*16384*8);      // 8 MB
  __bf16* w_in16 = (__bf16*)alloc((size_t)2*2048*256*2);        // 2 MB
  __bf16* w_xp16 = (__bf16*)alloc((size_t)2*48*1024*2);         // 0.19 MB
  __bf16* w_out16= (__bf16*)alloc((size_t)2*256*1024*2);        // 1 MB

  init_kernel<<<M_PAD + 512, 256, 0, stream>>>(x, res,
                                               in_w, w_in16, 2*2048*256,
                                               xp_w, w_xp16, 2*48*1024,
                                               out_w, w_out16, 2*256*1024);

  for (int i = 0; i < 2; ++i){
    rms_kernel<<<M_PAD, 256, 0, stream>>>(res, hn16, norm_w + i*256);
    // in_proj: M=4096 N=2048 K=256; 128x64 tile -> 1024 blocks = 4/CU
    gemm_tiled_kernel<4, 2, __bf16><<<dim3(32, 32), 256, 0, stream>>>(hn16, w_in16 + (size_t)i*524288, xz16, nullptr, 256, 2048);
    conv_xproj_dt_kernel<<<M_PAD/CBT, 256, 0, stream>>>(xz16, conv_w + i*4096, conv_b + i*1024,
                                                        w_xp16 + (size_t)i*49152, dt_w + i*16384, dt_b + i*1024,
                                                        u16, xdbl, delta16);
    scan_part1_kernel<<<4096, 256, 0, stream>>>(u16, delta16, xdbl, A_log + i*16384, Pq);
    scan_part2_kernel<<<4096, 256, 0, stream>>>(u16, delta16, xdbl, xz16, A_log + i*16384, Dp + i*1024,
                                                Pq, y16);
    // out_proj: M=4096 N=256 K=1024; 64x32 tile -> 512 blocks = 2/CU
    gemm_tiled_kernel<2, 1, float><<<dim3(64, 8), 256, 0, stream>>>(y16, w_out16 + (size_t)i*262144, res, res, 1024, 256);
  }
  fold_kernel<<<TLEN*4/256, 256, 0, stream>>>(x, res, out);
}

// Round 6
// 312.604 us; speedup vs baseline: 1.1201x; 1.1201x over previous
//
#include <hip/hip_runtime.h>
#include <cmath>

// ---- problem constants ----
#define DIMC   256
#define L_WIN  1023        // (131072-256)/128 + 1
#define M_VALID 4092       // 4*1023 tokens
#define M_PAD  4096
#define DI     1024        // D_INNER
#define TLEN   131072
#define SEG    64          // scan segment length
#define NSEG   16          // 16*64 = 1024 >= 1023
#define CBT    8           // tokens per conv_xproj block

typedef __bf16 bf16x8 __attribute__((ext_vector_type(8)));
typedef __bf16 bf16x4 __attribute__((ext_vector_type(4)));
typedef float  f32x4  __attribute__((ext_vector_type(4)));

#define LOG2E 1.4426950408889634f

__device__ __forceinline__ float sigmoidf_(float x){ return 1.f/(1.f + __expf(-x)); }
__device__ __forceinline__ float softplusf_(float v){ return fmaxf(v,0.f) + log1pf(__expf(-fabsf(v))); }

// DPP rotate-add: pure-VALU cross-lane sum step (no LDS traffic)
template<int CTRL>
__device__ __forceinline__ float dpp_add(float x){
  int v = __builtin_amdgcn_update_dpp(0, __builtin_bit_cast(int, x), CTRL, 0xF, 0xF, true);
  return x + __builtin_bit_cast(float, v);
}

// ---------------- init: frame (blocks 0..4095) + weight bf16 convert (blocks 4096+) ----------------
__global__ __launch_bounds__(256) void init_kernel(const float* __restrict__ x, float* __restrict__ res,
    const float* __restrict__ a, __bf16* __restrict__ da, int na,
    const float* __restrict__ b, __bf16* __restrict__ db, int nb,
    const float* __restrict__ c, __bf16* __restrict__ dc, int nc)
{
  if (blockIdx.x < M_PAD){
    int m = blockIdx.x, j = threadIdx.x;
    float v = 0.f;
    if (m < M_VALID){
      int bb = m / L_WIN, l = m - bb*L_WIN;
      v = x[(size_t)bb*TLEN + l*128 + j];
    }
    res[(size_t)m*DIMC + j] = v;
    return;
  }
  int nblk = gridDim.x - M_PAD;
  int stride = nblk*256;
  int base = (blockIdx.x - M_PAD)*256 + threadIdx.x;
  for (int i = base; i < na; i += stride) da[i] = (__bf16)a[i];
  for (int i = base; i < nb; i += stride) db[i] = (__bf16)b[i];
  for (int i = base; i < nc; i += stride) dc[i] = (__bf16)c[i];
}

// ---------------- rmsnorm row of 256 -> bf16 (kept separate: fusing into the GEMM
// recomputes row sums 16x per tile and regressed 27 us — r2 post-mortem) ----------------
__global__ __launch_bounds__(256) void rms_kernel(const float* __restrict__ src, __bf16* __restrict__ dst,
                                                  const float* __restrict__ w){
  int m = blockIdx.x, j = threadIdx.x;
  float v = (m < M_VALID) ? src[(size_t)m*DIMC + j] : 0.f;
  float s = v*v;
  #pragma unroll
  for (int off = 32; off; off >>= 1) s += __shfl_down(s, off);
  __shared__ float ls[4];
  if ((threadIdx.x & 63) == 0) ls[threadIdx.x >> 6] = s;
  __syncthreads();
  float tot = ls[0] + ls[1] + ls[2] + ls[3];
  float scale = rsqrtf(tot * (1.f/DIMC) + 1e-5f);
  dst[(size_t)m*DIMC + j] = (__bf16)(v * scale * w[j]);
}

// ======== LDS-tiled bf16 MFMA GEMM: C[M x N] = A[M x K] * B[N x K]^T (+addsrc) ========
// NOTE: C/addsrc NOT __restrict__ — out_proj call is in-place (C==addsrc).
template<int WM, int WN, typename OutT>
__global__ __launch_bounds__(256) void gemm_tiled_kernel(const __bf16* __restrict__ A, const __bf16* __restrict__ B,
    OutT* C, const float* addsrc, int K, int ldc)
{
  constexpr int BM  = 32*WM;
  constexpr int BN  = 32*WN;
  constexpr int LDK = 72;
  __shared__ __bf16 As[BM*LDK];
  __shared__ __bf16 Bs[BN*LDK];
  int tid  = threadIdx.x;
  int lane = tid & 63, wv = tid >> 6;
  int row  = lane & 15, kq = lane >> 4;
  int m0 = blockIdx.x*BM, n0 = blockIdx.y*BN;
  int wmo = (wv >> 1)*(16*WM);
  int wno = (wv &  1)*(16*WN);
  f32x4 acc[WM][WN] = {};
  for (int kt = 0; kt < K; kt += 64){
    __syncthreads();
    #pragma unroll
    for (int r = 0; r < BM/32; ++r){
      int seg = r*256 + tid;
      int rw = seg >> 3, sb = seg & 7;
      *(bf16x8*)(As + rw*LDK + sb*8) = *(const bf16x8*)(A + (size_t)(m0 + rw)*K + kt + sb*8);
    }
    #pragma unroll
    for (int r = 0; r < BN/32; ++r){
      int seg = r*256 + tid;
      int rw = seg >> 3, sb = seg & 7;
      *(bf16x8*)(Bs + rw*LDK + sb*8) = *(const bf16x8*)(B + (size_t)(n0 + rw)*K + kt + sb*8);
    }
    __syncthreads();
    #pragma unroll
    for (int ks = 0; ks < 2; ++ks){
      bf16x8 af[WM], bfr[WN];
      #pragma unroll
      for (int i = 0; i < WM; ++i) af[i]  = *(const bf16x8*)(As + (wmo + i*16 + row)*LDK + ks*32 + kq*8);
      #pragma unroll
      for (int j = 0; j < WN; ++j) bfr[j] = *(const bf16x8*)(Bs + (wno + j*16 + row)*LDK + ks*32 + kq*8);
      #pragma unroll
      for (int i = 0; i < WM; ++i){
        #pragma unroll
        for (int j = 0; j < WN; ++j)
          acc[i][j] = __builtin_amdgcn_mfma_f32_16x16x32_bf16(af[i], bfr[j], acc[i][j], 0, 0, 0);
      }
    }
  }
  #pragma unroll
  for (int i = 0; i < WM; ++i){
    int cm = m0 + wmo + i*16 + kq*4;
    #pragma unroll
    for (int j = 0; j < WN; ++j){
      int cn = n0 + wno + j*16 + row;
      #pragma unroll
      for (int ii = 0; ii < 4; ++ii){
        size_t idx = (size_t)(cm + ii)*ldc + cn;
        float v = acc[i][j][ii];
        if (addsrc) v += addsrc[idx];
        C[idx] = (OutT)v;
      }
    }
  }
}

// ======== fused conv4+SiLU -> xproj MFMA (K-split) -> dt_proj+softplus ========
__global__ __launch_bounds__(256) void conv_xproj_dt_kernel(
  const __bf16* __restrict__ xz16, const float* __restrict__ cw, const float* __restrict__ cb,
  const __bf16* __restrict__ wxp, const float* __restrict__ dtw, const float* __restrict__ dtb,
  __bf16* __restrict__ u16, float* __restrict__ xdbl, __bf16* __restrict__ delta16)
{
  __shared__ __bf16 su[16][1032];     // rows 0..CBT-1 valid; +8 pad
  __shared__ float  sdt[CBT][17];
  __shared__ f32x4  spart[4][3][64];  // [kwave][tile][lane] partial xproj sums
  int tid = threadIdx.x;
  int m0 = blockIdx.x * CBT;
  // ---- phase A: causal depthwise conv4 + bias + SiLU (rolling 4-row register window) ----
  {
    int d = tid * 4;
    float w[4][4], bias[4];
    #pragma unroll
    for (int c = 0; c < 4; ++c){
      #pragma unroll
      for (int j = 0; j < 4; ++j) w[c][j] = cw[(d + c)*4 + j];
      bias[c] = cb[d + c];
    }
    bf16x4 zero4; zero4[0] = (__bf16)0.f; zero4[1] = (__bf16)0.f; zero4[2] = (__bf16)0.f; zero4[3] = (__bf16)0.f;
    bf16x4 rm3 = (m0 >= 3) ? *(const bf16x4*)(xz16 + (size_t)(m0-3)*2048 + d) : zero4;
    bf16x4 rm2 = (m0 >= 2) ? *(const bf16x4*)(xz16 + (size_t)(m0-2)*2048 + d) : zero4;
    bf16x4 rm1 = (m0 >= 1) ? *(const bf16x4*)(xz16 + (size_t)(m0-1)*2048 + d) : zero4;
    for (int ti = 0; ti < CBT; ++ti){
      int m = m0 + ti;
      bf16x4 cur = *(const bf16x4*)(xz16 + (size_t)m*2048 + d);
      float acc[4] = {0.f, 0.f, 0.f, 0.f};
      if (m < M_VALID){
        int b = m / L_WIN;
        int l = m - b*L_WIN;
        #pragma unroll
        for (int c = 0; c < 4; ++c) acc[c] = fmaf((float)cur[c], w[c][3], bias[c]);
        if (l >= 1){
          #pragma unroll
          for (int c = 0; c < 4; ++c) acc[c] = fmaf((float)rm1[c], w[c][2], acc[c]);
        }
        if (l >= 2){
          #pragma unroll
          for (int c = 0; c < 4; ++c) acc[c] = fmaf((float)rm2[c], w[c][1], acc[c]);
        }
        if (l >= 3){
          #pragma unroll
          for (int c = 0; c < 4; ++c) acc[c] = fmaf((float)rm3[c], w[c][0], acc[c]);
        }
        #pragma unroll
        for (int c = 0; c < 4; ++c) acc[c] = acc[c] * sigmoidf_(acc[c]);
      }
      bf16x4 o;
      #pragma unroll
      for (int c = 0; c < 4; ++c) o[c] = (__bf16)acc[c];
      *(bf16x4*)(u16 + (size_t)m*DI + d) = o;
      *(bf16x4*)(&su[ti][d]) = o;
      rm3 = rm2; rm2 = rm1; rm1 = cur;
    }
  }
  __syncthreads();
  // ---- phase B: xproj, CBT tokens x 48 outputs, K=1024 split across 4 waves ----
  {
    int lane = tid & 63, wv = tid >> 6;
    int row = lane & 15, kq = lane >> 4;
    int kbase = wv * 256;
    f32x4 acc0 = {0,0,0,0}, acc1 = {0,0,0,0}, acc2 = {0,0,0,0};
    const __bf16* B0 = wxp + (size_t)(row)*1024      + kbase + kq*8;
    const __bf16* B1 = wxp + (size_t)(16 + row)*1024 + kbase + kq*8;
    const __bf16* B2 = wxp + (size_t)(32 + row)*1024 + kbase + kq*8;
    #pragma unroll
    for (int k = 0; k < 256; k += 32){
      bf16x8 a = *(const bf16x8*)(&su[row][kbase + k + kq*8]);
      acc0 = __builtin_amdgcn_mfma_f32_16x16x32_bf16(a, *(const bf16x8*)(B0 + k), acc0, 0, 0, 0);
      acc1 = __builtin_amdgcn_mfma_f32_16x16x32_bf16(a, *(const bf16x8*)(B1 + k), acc1, 0, 0, 0);
      acc2 = __builtin_amdgcn_mfma_f32_16x16x32_bf16(a, *(const bf16x8*)(B2 + k), acc2, 0, 0, 0);
    }
    spart[wv][0][lane] = acc0;
    spart[wv][1][lane] = acc1;
    spart[wv][2][lane] = acc2;
  }
  __syncthreads();
  // ---- reduce partials, write xdbl + sdt (only valid tokens) ----
  if (tid < 192){
    int tno = tid >> 6, lane = tid & 63;
    int row = lane & 15, kq = lane >> 4;
    f32x4 sum = spart[0][tno][lane];
    sum += spart[1][tno][lane];
    sum += spart[2][tno][lane];
    sum += spart[3][tno][lane];
    #pragma unroll
    for (int i = 0; i < 4; ++i){
      int tok = kq*4 + i;
      if (tok < CBT){
        xdbl[(size_t)(m0 + tok)*48 + tno*16 + row] = sum[i];
        if (tno == 0) sdt[tok][row] = sum[i];
      }
    }
  }
  __syncthreads();
  // ---- phase C: dt_proj (K=16) + softplus -> delta16 ----
  {
    int d0 = tid * 4;
    float w[4][16], bias[4];
    #pragma unroll
    for (int c = 0; c < 4; ++c){
      #pragma unroll
      for (int q = 0; q < 16; ++q) w[c][q] = dtw[(d0 + c)*16 + q];
      bias[c] = dtb[d0 + c];
    }
    for (int t = 0; t < CBT; ++t){
      float acc[4] = {bias[0], bias[1], bias[2], bias[3]};
      #pragma unroll
      for (int r = 0; r < 16; ++r){
        float dv = sdt[t][r];
        #pragma unroll
        for (int c = 0; c < 4; ++c) acc[c] = fmaf(dv, w[c][r], acc[c]);
      }
      bf16x4 o;
      #pragma unroll
      for (int c = 0; c < 4; ++c) o[c] = (__bf16)softplusf_(acc[c]);
      *(bf16x4*)(delta16 + (size_t)(m0 + t)*DI + d0) = o;
    }
  }
}

// ================= chunked two-phase selective scan =================
// r6: r3's exact skeleton (LDS 21.5 KB, 7 blocks/CU, 4-step DPP, 2 barriers —
// r4/r5 ledger: any LDS growth loses more via occupancy than VALU savings buy).
// Changes are pure instruction-count cuts in non-serial phases:
//  * staging: bf16x8 / f32x4 row loads (was 4096 scalar loads/block)
//  * part2 prefix: 4-wide batched Pq loads (was <=15 serial round-trips)
//  * part2 epilogue: bf16x8 z-loads + y-stores (was 1024 scalar 2B stores)
__global__ __launch_bounds__(256) void scan_part1_kernel(
  const __bf16* __restrict__ u16, const __bf16* __restrict__ delta16,
  const float* __restrict__ xdbl, const float* __restrict__ Alog, float2* __restrict__ Pq)
{
  int bid = blockIdx.x;
  int s = bid & 15, dtile = (bid >> 4) & 63, b = bid >> 10;
  int d0 = dtile << 4;
  int tid = threadIdx.x;
  int c = tid >> 4, n = tid & 15;
  float A2 = -__expf(Alog[(d0 + c)*16 + n]) * LOG2E;   // exp(dlt*A) = exp2(dlt*A2)
  __shared__ float2 sdd[16][SEG+2];   // (dlt, dlt*u)
  __shared__ float  sB [SEG][17];
  int t0 = s*SEG;
  int nt = L_WIN - t0; if (nt > SEG) nt = SEG;
  size_t base_m = (size_t)b*L_WIN + t0;
  // ---- vectorized staging: delta/u rows (threads 0..127), B quarters (all) ----
  if (tid < 128){
    int row = tid >> 1, half = tid & 1;
    bf16x8 dl8, u8;
    if (row < nt){
      size_t m = base_m + row;
      dl8 = *(const bf16x8*)(delta16 + m*DI + d0 + half*8);
      u8  = *(const bf16x8*)(u16    + m*DI + d0 + half*8);
    } else {
      #pragma unroll
      for (int j = 0; j < 8; ++j){ dl8[j] = (__bf16)0.f; u8[j] = (__bf16)0.f; }
    }
    #pragma unroll
    for (int j = 0; j < 8; ++j){
      float dlt = (float)dl8[j];
      sdd[half*8 + j][row] = make_float2(dlt, dlt * (float)u8[j]);
    }
  }
  {
    int row = tid & 63, q = tid >> 6;
    f32x4 B4 = {0,0,0,0};
    if (row < nt) B4 = *(const f32x4*)(xdbl + (base_m + row)*48 + 16 + q*4);
    #pragma unroll
    for (int j = 0; j < 4; ++j) sB[row][q*4 + j] = B4[j];
  }
  __syncthreads();
  float h = 0.f, sd = 0.f;
  #pragma unroll 8
  for (int t = 0; t < SEG; ++t){
    float2 dd2 = sdd[c][t];
    float dA = exp2f(dd2.x * A2);
    h = fmaf(dA, h, dd2.y * sB[t][n]);
    sd += dd2.x;                        // P = exp2(A2 * sum(dlt)): one exp2 at end
  }
  float P = exp2f(sd * A2);
  Pq[(((size_t)b*NSEG + s) << 14) + (dtile << 8) + tid] = make_float2(P, h);
}

__global__ __launch_bounds__(256) void scan_part2_kernel(
  const __bf16* __restrict__ u16, const __bf16* __restrict__ delta16,
  const float* __restrict__ xdbl, const __bf16* __restrict__ xz16,
  const float* __restrict__ Alog, const float* __restrict__ Dp,
  const float2* __restrict__ Pq, __bf16* __restrict__ y16)
{
  int bid = blockIdx.x;
  int s = bid & 15, dtile = (bid >> 4) & 63, b = bid >> 10;
  int d0 = dtile << 4;
  int tid = threadIdx.x;
  int c = tid >> 4, n = tid & 15;
  float A2 = -__expf(Alog[(d0 + c)*16 + n]) * LOG2E;
  __shared__ float2 sdd[16][SEG+2];   // (dlt, u)
  __shared__ float2 sBC[SEG][17];     // (B_n, C_n)
  __shared__ float  sy [16][SEG+1];
  __shared__ float  sD[16];
  if (tid < 16) sD[tid] = Dp[d0 + tid];
  int t0 = s*SEG;
  int nt = L_WIN - t0; if (nt > SEG) nt = SEG;
  size_t base_m = (size_t)b*L_WIN + t0;
  // ---- vectorized staging (issues before the prefix chain) ----
  if (tid < 128){
    int row = tid >> 1, half = tid & 1;
    bf16x8 dl8, u8;
    if (row < nt){
      size_t m = base_m + row;
      dl8 = *(const bf16x8*)(delta16 + m*DI + d0 + half*8);
      u8  = *(const bf16x8*)(u16    + m*DI + d0 + half*8);
    } else {
      #pragma unroll
      for (int j = 0; j < 8; ++j){ dl8[j] = (__bf16)0.f; u8[j] = (__bf16)0.f; }
    }
    #pragma unroll
    for (int j = 0; j < 8; ++j)
      sdd[half*8 + j][row] = make_float2((float)dl8[j], (float)u8[j]);
  }
  {
    int row = tid & 63, q = tid >> 6;
    f32x4 B4 = {0,0,0,0}, C4 = {0,0,0,0};
    if (row < nt){
      size_t m = base_m + row;
      B4 = *(const f32x4*)(xdbl + m*48 + 16 + q*4);
      C4 = *(const f32x4*)(xdbl + m*48 + 32 + q*4);
    }
    #pragma unroll
    for (int j = 0; j < 4; ++j) sBC[row][q*4 + j] = make_float2(B4[j], C4[j]);
  }
  // ---- batched prefix over earlier segments' (P,q): 4 loads in flight ----
  float h = 0.f;
  {
    size_t pqbase = (((size_t)b*NSEG) << 14) + (dtile << 8) + tid;
    for (int s0 = 0; s0 < 15; s0 += 4){
      if (s0 >= s) break;               // wave-uniform
      float2 r[4];
      #pragma unroll
      for (int j = 0; j < 4; ++j)
        r[j] = Pq[pqbase + ((size_t)(s0 + j) << 14)];   // sp<=14 always valid
      #pragma unroll
      for (int j = 0; j < 4; ++j)
        if (s0 + j < s) h = fmaf(r[j].x, h, r[j].y);
    }
  }
  __syncthreads();
  // ---- serial chain + 4-step DPP reduce (r3-identical) ----
  #pragma unroll 8
  for (int t = 0; t < SEG; ++t){
    float2 dd2 = sdd[c][t];
    float dA = exp2f(dd2.x * A2);
    float2 bc = sBC[t][n];
    h = fmaf(dA, h, dd2.x * dd2.y * bc.x);
    float pp = h * bc.y;
    pp = dpp_add<0xB1>(pp);    // xor1
    pp = dpp_add<0x4E>(pp);    // xor2
    pp = dpp_add<0x141>(pp);   // row_half_mirror
    pp = dpp_add<0x128>(pp);   // row_ror:8
    if (n == 0) sy[c][t] = pp;
  }
  __syncthreads();
  // ---- vectorized epilogue: threads 0..127, one half-row each ----
  if (tid < 128){
    int tt = tid >> 1, half = tid & 1;
    if (tt < nt){
      size_t m = base_m + tt;
      bf16x8 z8 = *(const bf16x8*)(xz16 + m*2048 + 1024 + d0 + half*8);
      bf16x8 o;
      #pragma unroll
      for (int j = 0; j < 8; ++j){
        int dd = half*8 + j;
        float zv = (float)z8[j];
        float yv = (sy[dd][tt] + sdd[dd][tt].y * sD[dd]) * (zv * sigmoidf_(zv));
        o[j] = (__bf16)yv;
      }
      *(bf16x8*)(y16 + m*DI + d0 + half*8) = o;
    }
  }
}

// ---------------- overlap-add fold + passthrough ----------------
__global__ __launch_bounds__(256) void fold_kernel(const float* __restrict__ x, const float* __restrict__ r,
                                                   float* __restrict__ out){
  int i = blockIdx.x*256 + threadIdx.x;
  int b = i >> 17;
  int t = i & (TLEN - 1);
  float acc = x[i];
  int l1 = t >> 7;
  int j  = t & 127;
  if (l1 < L_WIN) acc += r[((size_t)b*L_WIN + l1)*DIMC + j] * ((float)j * (1.f/127.f));
  if (l1 >= 1)    acc += r[((size_t)b*L_WIN + l1 - 1)*DIMC + j + 128] * ((float)(127 - j) * (1.f/127.f));
  out[i] = acc;
}

extern "C" void kernel_launch(void* const* d_in, const int* in_sizes, int n_in,
                              void* d_out, int out_size, void* d_ws, size_t ws_size,
                              hipStream_t stream)
{
  (void)in_sizes; (void)n_in; (void)out_size; (void)ws_size;
  const float* x      = (const float*)d_in[0];
  const float* in_w   = (const float*)d_in[1];
  const float* conv_w = (const float*)d_in[2];
  const float* conv_b = (const float*)d_in[3];
  const float* xp_w   = (const float*)d_in[4];
  const float* dt_w   = (const float*)d_in[5];
  const float* dt_b   = (const float*)d_in[6];
  const float* A_log  = (const float*)d_in[7];
  const float* Dp     = (const float*)d_in[8];
  const float* out_w  = (const float*)d_in[9];
  const float* norm_w = (const float*)d_in[10];
  float* out = (float*)d_out;

  // workspace layout (~56 MB; ws is 256 MiB)
  char* p = (char*)d_ws;
  auto alloc = [&](size_t bytes)->void*{ void* r = (void*)p; p += (bytes + 255) & ~(size_t)255; return r; };
  float*  res    = (float*) alloc((size_t)M_PAD*DIMC*4);        // 4 MB
  __bf16* hn16   = (__bf16*)alloc((size_t)M_PAD*DIMC*2);        // 2 MB
  __bf16* xz16   = (__bf16*)alloc((size_t)M_PAD*2048*2);        // 16 MB
  __bf16* u16    = (__bf16*)alloc((size_t)M_PAD*DI*2);          // 8 MB
  float*  xdbl   = (float*) alloc((size_t)M_PAD*48*4);          // 0.75 MB
  __bf16* delta16= (__bf16*)alloc((size_t)M_PAD*DI*2);          // 8 MB
  __bf16* y16    = (__bf16*)alloc((size_t)M_PAD*DI*2);          // 8 MB
  float2* Pq     = (float2*)alloc((size_t)4*NSEG*16384*8);      // 8 MB
  __bf16* w_in16 = (__bf16*)alloc((size_t)2*2048*256*2);        // 2 MB
  __bf16* w_xp16 = (__bf16*)alloc((size_t)2*48*1024*2);         // 0.19 MB
  __bf16* w_out16= (__bf16*)alloc((size_t)2*256*1024*2);        // 1 MB

  init_kernel<<<M_PAD + 512, 256, 0, stream>>>(x, res,
                                               in_w, w_in16, 2*2048*256,
                                               xp_w, w_xp16, 2*48*1024,
                                               out_w, w_out16, 2*256*1024);

  for (int i = 0; i < 2; ++i){
    rms_kernel<<<M_PAD, 256, 0, stream>>>(res, hn16, norm_w + i*256);
    // in_proj: M=4096 N=2048 K=256; 128x64 tile -> 1024 blocks = 4/CU
    gemm_tiled_kernel<4, 2, __bf16><<<dim3(32, 32), 256, 0, stream>>>(hn16, w_in16 + (size_t)i*524288, xz16, nullptr, 256, 2048);
    conv_xproj_dt_kernel<<<M_PAD/CBT, 256, 0, stream>>>(xz16, conv_w + i*4096, conv_b + i*1024,
                                                        w_xp16 + (size_t)i*49152, dt_w + i*16384, dt_b + i*1024,
                                                        u16, xdbl, delta16);
    scan_part1_kernel<<<4096, 256, 0, stream>>>(u16, delta16, xdbl, A_log + i*16384, Pq);
    scan_part2_kernel<<<4096, 256, 0, stream>>>(u16, delta16, xdbl, xz16, A_log + i*16384, Dp + i*1024,
                                                Pq, y16);
    // out_proj: M=4096 N=256 K=1024; 64x32 tile -> 512 blocks = 2/CU
    gemm_tiled_kernel<2, 1, float><<<dim3(64, 8), 256, 0, stream>>>(y16, w_out16 + (size_t)i*262144, res, res, 1024, 256);
  }
  fold_kernel<<<TLEN*4/256, 256, 0, stream>>>(x, res, out);
}

// Round 7
// 309.307 us; speedup vs baseline: 1.1321x; 1.0107x over previous
//
#include <hip/hip_runtime.h>
#include <cmath>

// ---- problem constants ----
#define DIMC   256
#define L_WIN  1023        // (131072-256)/128 + 1
#define M_VALID 4092       // 4*1023 tokens
#define M_PAD  4096
#define DI     1024        // D_INNER
#define TLEN   131072
#define SEG    64          // scan segment length
#define NSEG   16          // 16*64 = 1024 >= 1023
#define CBT    8           // tokens per conv_xproj block

typedef __bf16 bf16x8 __attribute__((ext_vector_type(8)));
typedef __bf16 bf16x4 __attribute__((ext_vector_type(4)));
typedef float  f32x4  __attribute__((ext_vector_type(4)));

#define LOG2E 1.4426950408889634f

__device__ __forceinline__ float sigmoidf_(float x){ return 1.f/(1.f + __expf(-x)); }
__device__ __forceinline__ float softplusf_(float v){ return fmaxf(v,0.f) + log1pf(__expf(-fabsf(v))); }

// DPP rotate-add: pure-VALU cross-lane sum step (no LDS traffic)
template<int CTRL>
__device__ __forceinline__ float dpp_add(float x){
  int v = __builtin_amdgcn_update_dpp(0, __builtin_bit_cast(int, x), CTRL, 0xF, 0xF, true);
  return x + __builtin_bit_cast(float, v);
}

// ---------------- init: frame (blocks 0..4095) + weight bf16 convert (blocks 4096+) ----------------
__global__ __launch_bounds__(256) void init_kernel(const float* __restrict__ x, float* __restrict__ res,
    const float* __restrict__ a, __bf16* __restrict__ da, int na,
    const float* __restrict__ b, __bf16* __restrict__ db, int nb,
    const float* __restrict__ c, __bf16* __restrict__ dc, int nc)
{
  if (blockIdx.x < M_PAD){
    int m = blockIdx.x, j = threadIdx.x;
    float v = 0.f;
    if (m < M_VALID){
      int bb = m / L_WIN, l = m - bb*L_WIN;
      v = x[(size_t)bb*TLEN + l*128 + j];
    }
    res[(size_t)m*DIMC + j] = v;
    return;
  }
  int nblk = gridDim.x - M_PAD;
  int stride = nblk*256;
  int base = (blockIdx.x - M_PAD)*256 + threadIdx.x;
  for (int i = base; i < na; i += stride) da[i] = (__bf16)a[i];
  for (int i = base; i < nb; i += stride) db[i] = (__bf16)b[i];
  for (int i = base; i < nc; i += stride) dc[i] = (__bf16)c[i];
}

// ---------------- rmsnorm row of 256 -> bf16 (kept separate: fusing into the GEMM
// recomputes row sums 16x per tile and regressed 27 us — r2 post-mortem) ----------------
__global__ __launch_bounds__(256) void rms_kernel(const float* __restrict__ src, __bf16* __restrict__ dst,
                                                  const float* __restrict__ w){
  int m = blockIdx.x, j = threadIdx.x;
  float v = (m < M_VALID) ? src[(size_t)m*DIMC + j] : 0.f;
  float s = v*v;
  #pragma unroll
  for (int off = 32; off; off >>= 1) s += __shfl_down(s, off);
  __shared__ float ls[4];
  if ((threadIdx.x & 63) == 0) ls[threadIdx.x >> 6] = s;
  __syncthreads();
  float tot = ls[0] + ls[1] + ls[2] + ls[3];
  float scale = rsqrtf(tot * (1.f/DIMC) + 1e-5f);
  dst[(size_t)m*DIMC + j] = (__bf16)(v * scale * w[j]);
}

// ======== LDS-tiled bf16 MFMA GEMM: C[M x N] = A[M x K] * B[N x K]^T (+addsrc) ========
// NOTE: C/addsrc NOT __restrict__ — out_proj call is in-place (C==addsrc).
template<int WM, int WN, typename OutT>
__global__ __launch_bounds__(256) void gemm_tiled_kernel(const __bf16* __restrict__ A, const __bf16* __restrict__ B,
    OutT* C, const float* addsrc, int K, int ldc)
{
  constexpr int BM  = 32*WM;
  constexpr int BN  = 32*WN;
  constexpr int LDK = 72;
  __shared__ __bf16 As[BM*LDK];
  __shared__ __bf16 Bs[BN*LDK];
  int tid  = threadIdx.x;
  int lane = tid & 63, wv = tid >> 6;
  int row  = lane & 15, kq = lane >> 4;
  int m0 = blockIdx.x*BM, n0 = blockIdx.y*BN;
  int wmo = (wv >> 1)*(16*WM);
  int wno = (wv &  1)*(16*WN);
  f32x4 acc[WM][WN] = {};
  for (int kt = 0; kt < K; kt += 64){
    __syncthreads();
    #pragma unroll
    for (int r = 0; r < BM/32; ++r){
      int seg = r*256 + tid;
      int rw = seg >> 3, sb = seg & 7;
      *(bf16x8*)(As + rw*LDK + sb*8) = *(const bf16x8*)(A + (size_t)(m0 + rw)*K + kt + sb*8);
    }
    #pragma unroll
    for (int r = 0; r < BN/32; ++r){
      int seg = r*256 + tid;
      int rw = seg >> 3, sb = seg & 7;
      *(bf16x8*)(Bs + rw*LDK + sb*8) = *(const bf16x8*)(B + (size_t)(n0 + rw)*K + kt + sb*8);
    }
    __syncthreads();
    #pragma unroll
    for (int ks = 0; ks < 2; ++ks){
      bf16x8 af[WM], bfr[WN];
      #pragma unroll
      for (int i = 0; i < WM; ++i) af[i]  = *(const bf16x8*)(As + (wmo + i*16 + row)*LDK + ks*32 + kq*8);
      #pragma unroll
      for (int j = 0; j < WN; ++j) bfr[j] = *(const bf16x8*)(Bs + (wno + j*16 + row)*LDK + ks*32 + kq*8);
      #pragma unroll
      for (int i = 0; i < WM; ++i){
        #pragma unroll
        for (int j = 0; j < WN; ++j)
          acc[i][j] = __builtin_amdgcn_mfma_f32_16x16x32_bf16(af[i], bfr[j], acc[i][j], 0, 0, 0);
      }
    }
  }
  #pragma unroll
  for (int i = 0; i < WM; ++i){
    int cm = m0 + wmo + i*16 + kq*4;
    #pragma unroll
    for (int j = 0; j < WN; ++j){
      int cn = n0 + wno + j*16 + row;
      #pragma unroll
      for (int ii = 0; ii < 4; ++ii){
        size_t idx = (size_t)(cm + ii)*ldc + cn;
        float v = acc[i][j][ii];
        if (addsrc) v += addsrc[idx];
        C[idx] = (OutT)v;
      }
    }
  }
}

// ======== fused conv4+SiLU -> xproj MFMA (K-split) -> dt_proj+softplus ========
__global__ __launch_bounds__(256) void conv_xproj_dt_kernel(
  const __bf16* __restrict__ xz16, const float* __restrict__ cw, const float* __restrict__ cb,
  const __bf16* __restrict__ wxp, const float* __restrict__ dtw, const float* __restrict__ dtb,
  __bf16* __restrict__ u16, float* __restrict__ xdbl, __bf16* __restrict__ delta16)
{
  __shared__ __bf16 su[16][1032];     // rows 0..CBT-1 valid; +8 pad
  __shared__ float  sdt[CBT][17];
  __shared__ f32x4  spart[4][3][64];  // [kwave][tile][lane] partial xproj sums
  int tid = threadIdx.x;
  int m0 = blockIdx.x * CBT;
  // ---- phase A: causal depthwise conv4 + bias + SiLU (rolling 4-row register window) ----
  {
    int d = tid * 4;
    float w[4][4], bias[4];
    #pragma unroll
    for (int c = 0; c < 4; ++c){
      #pragma unroll
      for (int j = 0; j < 4; ++j) w[c][j] = cw[(d + c)*4 + j];
      bias[c] = cb[d + c];
    }
    bf16x4 zero4; zero4[0] = (__bf16)0.f; zero4[1] = (__bf16)0.f; zero4[2] = (__bf16)0.f; zero4[3] = (__bf16)0.f;
    bf16x4 rm3 = (m0 >= 3) ? *(const bf16x4*)(xz16 + (size_t)(m0-3)*2048 + d) : zero4;
    bf16x4 rm2 = (m0 >= 2) ? *(const bf16x4*)(xz16 + (size_t)(m0-2)*2048 + d) : zero4;
    bf16x4 rm1 = (m0 >= 1) ? *(const bf16x4*)(xz16 + (size_t)(m0-1)*2048 + d) : zero4;
    for (int ti = 0; ti < CBT; ++ti){
      int m = m0 + ti;
      bf16x4 cur = *(const bf16x4*)(xz16 + (size_t)m*2048 + d);
      float acc[4] = {0.f, 0.f, 0.f, 0.f};
      if (m < M_VALID){
        int b = m / L_WIN;
        int l = m - b*L_WIN;
        #pragma unroll
        for (int c = 0; c < 4; ++c) acc[c] = fmaf((float)cur[c], w[c][3], bias[c]);
        if (l >= 1){
          #pragma unroll
          for (int c = 0; c < 4; ++c) acc[c] = fmaf((float)rm1[c], w[c][2], acc[c]);
        }
        if (l >= 2){
          #pragma unroll
          for (int c = 0; c < 4; ++c) acc[c] = fmaf((float)rm2[c], w[c][1], acc[c]);
        }
        if (l >= 3){
          #pragma unroll
          for (int c = 0; c < 4; ++c) acc[c] = fmaf((float)rm3[c], w[c][0], acc[c]);
        }
        #pragma unroll
        for (int c = 0; c < 4; ++c) acc[c] = acc[c] * sigmoidf_(acc[c]);
      }
      bf16x4 o;
      #pragma unroll
      for (int c = 0; c < 4; ++c) o[c] = (__bf16)acc[c];
      *(bf16x4*)(u16 + (size_t)m*DI + d) = o;
      *(bf16x4*)(&su[ti][d]) = o;
      rm3 = rm2; rm2 = rm1; rm1 = cur;
    }
  }
  __syncthreads();
  // ---- phase B: xproj, CBT tokens x 48 outputs, K=1024 split across 4 waves ----
  {
    int lane = tid & 63, wv = tid >> 6;
    int row = lane & 15, kq = lane >> 4;
    int kbase = wv * 256;
    f32x4 acc0 = {0,0,0,0}, acc1 = {0,0,0,0}, acc2 = {0,0,0,0};
    const __bf16* B0 = wxp + (size_t)(row)*1024      + kbase + kq*8;
    const __bf16* B1 = wxp + (size_t)(16 + row)*1024 + kbase + kq*8;
    const __bf16* B2 = wxp + (size_t)(32 + row)*1024 + kbase + kq*8;
    #pragma unroll
    for (int k = 0; k < 256; k += 32){
      bf16x8 a = *(const bf16x8*)(&su[row][kbase + k + kq*8]);
      acc0 = __builtin_amdgcn_mfma_f32_16x16x32_bf16(a, *(const bf16x8*)(B0 + k), acc0, 0, 0, 0);
      acc1 = __builtin_amdgcn_mfma_f32_16x16x32_bf16(a, *(const bf16x8*)(B1 + k), acc1, 0, 0, 0);
      acc2 = __builtin_amdgcn_mfma_f32_16x16x32_bf16(a, *(const bf16x8*)(B2 + k), acc2, 0, 0, 0);
    }
    spart[wv][0][lane] = acc0;
    spart[wv][1][lane] = acc1;
    spart[wv][2][lane] = acc2;
  }
  __syncthreads();
  // ---- reduce partials, write xdbl + sdt (only valid tokens) ----
  if (tid < 192){
    int tno = tid >> 6, lane = tid & 63;
    int row = lane & 15, kq = lane >> 4;
    f32x4 sum = spart[0][tno][lane];
    sum += spart[1][tno][lane];
    sum += spart[2][tno][lane];
    sum += spart[3][tno][lane];
    #pragma unroll
    for (int i = 0; i < 4; ++i){
      int tok = kq*4 + i;
      if (tok < CBT){
        xdbl[(size_t)(m0 + tok)*48 + tno*16 + row] = sum[i];
        if (tno == 0) sdt[tok][row] = sum[i];
      }
    }
  }
  __syncthreads();
  // ---- phase C: dt_proj (K=16) + softplus -> delta16 ----
  {
    int d0 = tid * 4;
    float w[4][16], bias[4];
    #pragma unroll
    for (int c = 0; c < 4; ++c){
      #pragma unroll
      for (int q = 0; q < 16; ++q) w[c][q] = dtw[(d0 + c)*16 + q];
      bias[c] = dtb[d0 + c];
    }
    for (int t = 0; t < CBT; ++t){
      float acc[4] = {bias[0], bias[1], bias[2], bias[3]};
      #pragma unroll
      for (int r = 0; r < 16; ++r){
        float dv = sdt[t][r];
        #pragma unroll
        for (int c = 0; c < 4; ++c) acc[c] = fmaf(dv, w[c][r], acc[c]);
      }
      bf16x4 o;
      #pragma unroll
      for (int c = 0; c < 4; ++c) o[c] = (__bf16)softplusf_(acc[c]);
      *(bf16x4*)(delta16 + (size_t)(m0 + t)*DI + d0) = o;
    }
  }
}

// ================= chunked two-phase selective scan =================
__global__ __launch_bounds__(256) void scan_part1_kernel(
  const __bf16* __restrict__ u16, const __bf16* __restrict__ delta16,
  const float* __restrict__ xdbl, const float* __restrict__ Alog, float2* __restrict__ Pq)
{
  int bid = blockIdx.x;
  int s = bid & 15, dtile = (bid >> 4) & 63, b = bid >> 10;
  int d0 = dtile << 4;
  int tid = threadIdx.x;
  int c = tid >> 4, n = tid & 15;
  float A2 = -__expf(Alog[(d0 + c)*16 + n]) * LOG2E;   // exp(dlt*A) = exp2(dlt*A2)
  __shared__ float2 sdd[16][SEG+2];   // (dlt, dlt*u)
  __shared__ float  sB [SEG][17];
  int t0 = s*SEG;
  int nt = L_WIN - t0; if (nt > SEG) nt = SEG;
  size_t base_m = (size_t)b*L_WIN + t0;
  // ---- vectorized staging: delta/u rows (threads 0..127), B quarters (all) ----
  if (tid < 128){
    int row = tid >> 1, half = tid & 1;
    bf16x8 dl8, u8;
    if (row < nt){
      size_t m = base_m + row;
      dl8 = *(const bf16x8*)(delta16 + m*DI + d0 + half*8);
      u8  = *(const bf16x8*)(u16    + m*DI + d0 + half*8);
    } else {
      #pragma unroll
      for (int j = 0; j < 8; ++j){ dl8[j] = (__bf16)0.f; u8[j] = (__bf16)0.f; }
    }
    #pragma unroll
    for (int j = 0; j < 8; ++j){
      float dlt = (float)dl8[j];
      sdd[half*8 + j][row] = make_float2(dlt, dlt * (float)u8[j]);
    }
  }
  {
    int row = tid & 63, q = tid >> 6;
    f32x4 B4 = {0,0,0,0};
    if (row < nt) B4 = *(const f32x4*)(xdbl + (base_m + row)*48 + 16 + q*4);
    #pragma unroll
    for (int j = 0; j < 4; ++j) sB[row][q*4 + j] = B4[j];
  }
  __syncthreads();
  float h = 0.f, sd = 0.f;
  #pragma unroll 8
  for (int t = 0; t < SEG; ++t){
    float2 dd2 = sdd[c][t];
    float dA = exp2f(dd2.x * A2);
    h = fmaf(dA, h, dd2.y * sB[t][n]);
    sd += dd2.x;                        // P = exp2(A2 * sum(dlt)): one exp2 at end
  }
  float P = exp2f(sd * A2);
  Pq[(((size_t)b*NSEG + s) << 14) + (dtile << 8) + tid] = make_float2(P, h);
}

// r7: residency-quantization fix. r6's part2 used 21.5 KB LDS -> 7 blocks/CU
// vs grid 16/CU = 2.29 ragged passes (the 76% VALUBusy / 51% Occ signature).
// sy buffer ELIMINATED: the reduced pp is written into the just-consumed
// sdd[c][t].x slot (dlt is dead after its token; rows c are wave-private —
// wave w owns c in [4w,4w+4) — so no cross-wave race). LDS 17.2 KB ->
// 8 blocks/CU, 16/8 = 2.0 integer passes. Also: staging pre-multiplies
// (dlt, dlt*u) (same mul order as the old in-loop product — bit-identical),
// saving 1 VALU/token in the serial chain; epilogue reloads u16 (L2-hot).
__global__ __launch_bounds__(256) void scan_part2_kernel(
  const __bf16* __restrict__ u16, const __bf16* __restrict__ delta16,
  const float* __restrict__ xdbl, const __bf16* __restrict__ xz16,
  const float* __restrict__ Alog, const float* __restrict__ Dp,
  const float2* __restrict__ Pq, __bf16* __restrict__ y16)
{
  int bid = blockIdx.x;
  int s = bid & 15, dtile = (bid >> 4) & 63, b = bid >> 10;
  int d0 = dtile << 4;
  int tid = threadIdx.x;
  int c = tid >> 4, n = tid & 15;
  float A2 = -__expf(Alog[(d0 + c)*16 + n]) * LOG2E;
  __shared__ float2 sdd[16][SEG+2];   // (dlt, dlt*u); .x becomes y-pre after serial
  __shared__ float2 sBC[SEG][17];     // (B_n, C_n)
  __shared__ float  sD[16];
  if (tid < 16) sD[tid] = Dp[d0 + tid];
  int t0 = s*SEG;
  int nt = L_WIN - t0; if (nt > SEG) nt = SEG;
  size_t base_m = (size_t)b*L_WIN + t0;
  // ---- vectorized staging (issues before the prefix chain) ----
  if (tid < 128){
    int row = tid >> 1, half = tid & 1;
    bf16x8 dl8, u8;
    if (row < nt){
      size_t m = base_m + row;
      dl8 = *(const bf16x8*)(delta16 + m*DI + d0 + half*8);
      u8  = *(const bf16x8*)(u16    + m*DI + d0 + half*8);
    } else {
      #pragma unroll
      for (int j = 0; j < 8; ++j){ dl8[j] = (__bf16)0.f; u8[j] = (__bf16)0.f; }
    }
    #pragma unroll
    for (int j = 0; j < 8; ++j){
      float dlt = (float)dl8[j];
      sdd[half*8 + j][row] = make_float2(dlt, dlt * (float)u8[j]);
    }
  }
  {
    int row = tid & 63, q = tid >> 6;
    f32x4 B4 = {0,0,0,0}, C4 = {0,0,0,0};
    if (row < nt){
      size_t m = base_m + row;
      B4 = *(const f32x4*)(xdbl + m*48 + 16 + q*4);
      C4 = *(const f32x4*)(xdbl + m*48 + 32 + q*4);
    }
    #pragma unroll
    for (int j = 0; j < 4; ++j) sBC[row][q*4 + j] = make_float2(B4[j], C4[j]);
  }
  // ---- batched prefix over earlier segments' (P,q): 4 loads in flight ----
  float h = 0.f;
  {
    size_t pqbase = (((size_t)b*NSEG) << 14) + (dtile << 8) + tid;
    for (int s0 = 0; s0 < 15; s0 += 4){
      if (s0 >= s) break;               // wave-uniform
      float2 r[4];
      #pragma unroll
      for (int j = 0; j < 4; ++j)
        r[j] = Pq[pqbase + ((size_t)(s0 + j) << 14)];   // sp<=14 always valid
      #pragma unroll
      for (int j = 0; j < 4; ++j)
        if (s0 + j < s) h = fmaf(r[j].x, h, r[j].y);
    }
  }
  __syncthreads();
  // ---- serial chain + 4-step DPP reduce; pp lands in sdd[c][t].x ----
  #pragma unroll 8
  for (int t = 0; t < SEG; ++t){
    float2 dd2 = sdd[c][t];
    float dA = exp2f(dd2.x * A2);
    float2 bc = sBC[t][n];
    h = fmaf(dA, h, dd2.y * bc.x);
    float pp = h * bc.y;
    pp = dpp_add<0xB1>(pp);    // xor1
    pp = dpp_add<0x4E>(pp);    // xor2
    pp = dpp_add<0x141>(pp);   // row_half_mirror
    pp = dpp_add<0x128>(pp);   // row_ror:8
    if (n == 0) sdd[c][t].x = pp;   // overwrite consumed dlt slot (wave-private row)
  }
  __syncthreads();
  // ---- vectorized epilogue: threads 0..127, one half-row each ----
  if (tid < 128){
    int tt = tid >> 1, half = tid & 1;
    if (tt < nt){
      size_t m = base_m + tt;
      bf16x8 z8 = *(const bf16x8*)(xz16 + m*2048 + 1024 + d0 + half*8);
      bf16x8 u8 = *(const bf16x8*)(u16 + m*DI + d0 + half*8);
      bf16x8 o;
      #pragma unroll
      for (int j = 0; j < 8; ++j){
        int dd = half*8 + j;
        float zv = (float)z8[j];
        float yv = (sdd[dd][tt].x + (float)u8[j] * sD[dd]) * (zv * sigmoidf_(zv));
        o[j] = (__bf16)yv;
      }
      *(bf16x8*)(y16 + m*DI + d0 + half*8) = o;
    }
  }
}

// ---------------- overlap-add fold + passthrough ----------------
__global__ __launch_bounds__(256) void fold_kernel(const float* __restrict__ x, const float* __restrict__ r,
                                                   float* __restrict__ out){
  int i = blockIdx.x*256 + threadIdx.x;
  int b = i >> 17;
  int t = i & (TLEN - 1);
  float acc = x[i];
  int l1 = t >> 7;
  int j  = t & 127;
  if (l1 < L_WIN) acc += r[((size_t)b*L_WIN + l1)*DIMC + j] * ((float)j * (1.f/127.f));
  if (l1 >= 1)    acc += r[((size_t)b*L_WIN + l1 - 1)*DIMC + j + 128] * ((float)(127 - j) * (1.f/127.f));
  out[i] = acc;
}

extern "C" void kernel_launch(void* const* d_in, const int* in_sizes, int n_in,
                              void* d_out, int out_size, void* d_ws, size_t ws_size,
                              hipStream_t stream)
{
  (void)in_sizes; (void)n_in; (void)out_size; (void)ws_size;
  const float* x      = (const float*)d_in[0];
  const float* in_w   = (const float*)d_in[1];
  const float* conv_w = (const float*)d_in[2];
  const float* conv_b = (const float*)d_in[3];
  const float* xp_w   = (const float*)d_in[4];
  const float* dt_w   = (const float*)d_in[5];
  const float* dt_b   = (const float*)d_in[6];
  const float* A_log  = (const float*)d_in[7];
  const float* Dp     = (const float*)d_in[8];
  const float* out_w  = (const float*)d_in[9];
  const float* norm_w = (const float*)d_in[10];
  float* out = (float*)d_out;

  // workspace layout (~56 MB; ws is 256 MiB)
  char* p = (char*)d_ws;
  auto alloc = [&](size_t bytes)->void*{ void* r = (void*)p; p += (bytes + 255) & ~(size_t)255; return r; };
  float*  res    = (float*) alloc((size_t)M_PAD*DIMC*4);        // 4 MB
  __bf16* hn16   = (__bf16*)alloc((size_t)M_PAD*DIMC*2);        // 2 MB
  __bf16* xz16   = (__bf16*)alloc((size_t)M_PAD*2048*2);        // 16 MB
  __bf16* u16    = (__bf16*)alloc((size_t)M_PAD*DI*2);          // 8 MB
  float*  xdbl   = (float*) alloc((size_t)M_PAD*48*4);          // 0.75 MB
  __bf16* delta16= (__bf16*)alloc((size_t)M_PAD*DI*2);          // 8 MB
  __bf16* y16    = (__bf16*)alloc((size_t)M_PAD*DI*2);          // 8 MB
  float2* Pq     = (float2*)alloc((size_t)4*NSEG*16384*8);      // 8 MB
  __bf16* w_in16 = (__bf16*)alloc((size_t)2*2048*256*2);        // 2 MB
  __bf16* w_xp16 = (__bf16*)alloc((size_t)2*48*1024*2);         // 0.19 MB
  __bf16* w_out16= (__bf16*)alloc((size_t)2*256*1024*2);        // 1 MB

  init_kernel<<<M_PAD + 512, 256, 0, stream>>>(x, res,
                                               in_w, w_in16, 2*2048*256,
                                               xp_w, w_xp16, 2*48*1024,
                                               out_w, w_out16, 2*256*1024);

  for (int i = 0; i < 2; ++i){
    rms_kernel<<<M_PAD, 256, 0, stream>>>(res, hn16, norm_w + i*256);
    // in_proj: M=4096 N=2048 K=256; 128x64 tile -> 1024 blocks = 4/CU
    gemm_tiled_kernel<4, 2, __bf16><<<dim3(32, 32), 256, 0, stream>>>(hn16, w_in16 + (size_t)i*524288, xz16, nullptr, 256, 2048);
    conv_xproj_dt_kernel<<<M_PAD/CBT, 256, 0, stream>>>(xz16, conv_w + i*4096, conv_b + i*1024,
                                                        w_xp16 + (size_t)i*49152, dt_w + i*16384, dt_b + i*1024,
                                                        u16, xdbl, delta16);
    scan_part1_kernel<<<4096, 256, 0, stream>>>(u16, delta16, xdbl, A_log + i*16384, Pq);
    scan_part2_kernel<<<4096, 256, 0, stream>>>(u16, delta16, xdbl, xz16, A_log + i*16384, Dp + i*1024,
                                                Pq, y16);
    // out_proj: M=4096 N=256 K=1024; 64x32 tile -> 512 blocks = 2/CU
    gemm_tiled_kernel<2, 1, float><<<dim3(64, 8), 256, 0, stream>>>(y16, w_out16 + (size_t)i*262144, res, res, 1024, 256);
  }
  fold_kernel<<<TLEN*4/256, 256, 0, stream>>>(x, res, out);
}

// Round 8
// 301.801 us; speedup vs baseline: 1.1602x; 1.0249x over previous
//
#include <hip/hip_runtime.h>
#include <cmath>

// ---- problem constants ----
#define DIMC   256
#define L_WIN  1023        // (131072-256)/128 + 1
#define M_VALID 4092       // 4*1023 tokens
#define M_PAD  4096
#define DI     1024        // D_INNER
#define TLEN   131072
#define SEG    64          // scan segment length
#define NSEG   16          // 16*64 = 1024 >= 1023
#define CBT    8           // tokens per conv_xproj block

typedef __bf16 bf16x8 __attribute__((ext_vector_type(8)));
typedef __bf16 bf16x4 __attribute__((ext_vector_type(4)));
typedef float  f32x4  __attribute__((ext_vector_type(4)));

#define LOG2E 1.4426950408889634f

__device__ __forceinline__ float sigmoidf_(float x){ return 1.f/(1.f + __expf(-x)); }
__device__ __forceinline__ float softplusf_(float v){ return fmaxf(v,0.f) + log1pf(__expf(-fabsf(v))); }

// DPP rotate-add: pure-VALU cross-lane sum step (no LDS traffic)
template<int CTRL>
__device__ __forceinline__ float dpp_add(float x){
  int v = __builtin_amdgcn_update_dpp(0, __builtin_bit_cast(int, x), CTRL, 0xF, 0xF, true);
  return x + __builtin_bit_cast(float, v);
}

// ---------------- init: frame + LAYER-0 RMSNORM (blocks 0..4095) + weight convert (4096+) ----------
// r8: each init block owns a complete row of res -> the row-local rms reduction
// fuses for free (unlike r2's failed GEMM fusion which recomputed sums 16x).
__global__ __launch_bounds__(256) void init_kernel(const float* __restrict__ x, float* __restrict__ res,
    __bf16* __restrict__ hn16, const float* __restrict__ w0,
    const float* __restrict__ a, __bf16* __restrict__ da, int na,
    const float* __restrict__ b, __bf16* __restrict__ db, int nb,
    const float* __restrict__ c, __bf16* __restrict__ dc, int nc)
{
  if (blockIdx.x < M_PAD){
    int m = blockIdx.x, j = threadIdx.x;
    float v = 0.f;
    if (m < M_VALID){
      int bb = m / L_WIN, l = m - bb*L_WIN;
      v = x[(size_t)bb*TLEN + l*128 + j];
    }
    res[(size_t)m*DIMC + j] = v;
    // ---- layer-0 rms fused ----
    float s = v*v;
    #pragma unroll
    for (int off = 32; off; off >>= 1) s += __shfl_down(s, off);
    __shared__ float ls[4];
    if ((threadIdx.x & 63) == 0) ls[threadIdx.x >> 6] = s;
    __syncthreads();
    float tot = ls[0] + ls[1] + ls[2] + ls[3];
    float scale = rsqrtf(tot * (1.f/DIMC) + 1e-5f);
    hn16[(size_t)m*DIMC + j] = (__bf16)(v * scale * w0[j]);
    return;
  }
  int nblk = gridDim.x - M_PAD;
  int stride = nblk*256;
  int base = (blockIdx.x - M_PAD)*256 + threadIdx.x;
  for (int i = base; i < na; i += stride) da[i] = (__bf16)a[i];
  for (int i = base; i < nb; i += stride) db[i] = (__bf16)b[i];
  for (int i = base; i < nc; i += stride) dc[i] = (__bf16)c[i];
}

// ---------------- rmsnorm row of 256 -> bf16 (layer 1 only; layer 0 fused into init) ------------
__global__ __launch_bounds__(256) void rms_kernel(const float* __restrict__ src, __bf16* __restrict__ dst,
                                                  const float* __restrict__ w){
  int m = blockIdx.x, j = threadIdx.x;
  float v = (m < M_VALID) ? src[(size_t)m*DIMC + j] : 0.f;
  float s = v*v;
  #pragma unroll
  for (int off = 32; off; off >>= 1) s += __shfl_down(s, off);
  __shared__ float ls[4];
  if ((threadIdx.x & 63) == 0) ls[threadIdx.x >> 6] = s;
  __syncthreads();
  float tot = ls[0] + ls[1] + ls[2] + ls[3];
  float scale = rsqrtf(tot * (1.f/DIMC) + 1e-5f);
  dst[(size_t)m*DIMC + j] = (__bf16)(v * scale * w[j]);
}

// ======== LDS-tiled bf16 MFMA GEMM: C[M x N] = A[M x K] * B[N x K]^T (+addsrc) ========
// NOTE: C/addsrc NOT __restrict__ — out_proj call is in-place (C==addsrc).
template<int WM, int WN, typename OutT>
__global__ __launch_bounds__(256) void gemm_tiled_kernel(const __bf16* __restrict__ A, const __bf16* __restrict__ B,
    OutT* C, const float* addsrc, int K, int ldc)
{
  constexpr int BM  = 32*WM;
  constexpr int BN  = 32*WN;
  constexpr int LDK = 72;
  __shared__ __bf16 As[BM*LDK];
  __shared__ __bf16 Bs[BN*LDK];
  int tid  = threadIdx.x;
  int lane = tid & 63, wv = tid >> 6;
  int row  = lane & 15, kq = lane >> 4;
  int m0 = blockIdx.x*BM, n0 = blockIdx.y*BN;
  int wmo = (wv >> 1)*(16*WM);
  int wno = (wv &  1)*(16*WN);
  f32x4 acc[WM][WN] = {};
  for (int kt = 0; kt < K; kt += 64){
    __syncthreads();
    #pragma unroll
    for (int r = 0; r < BM/32; ++r){
      int seg = r*256 + tid;
      int rw = seg >> 3, sb = seg & 7;
      *(bf16x8*)(As + rw*LDK + sb*8) = *(const bf16x8*)(A + (size_t)(m0 + rw)*K + kt + sb*8);
    }
    #pragma unroll
    for (int r = 0; r < BN/32; ++r){
      int seg = r*256 + tid;
      int rw = seg >> 3, sb = seg & 7;
      *(bf16x8*)(Bs + rw*LDK + sb*8) = *(const bf16x8*)(B + (size_t)(n0 + rw)*K + kt + sb*8);
    }
    __syncthreads();
    #pragma unroll
    for (int ks = 0; ks < 2; ++ks){
      bf16x8 af[WM], bfr[WN];
      #pragma unroll
      for (int i = 0; i < WM; ++i) af[i]  = *(const bf16x8*)(As + (wmo + i*16 + row)*LDK + ks*32 + kq*8);
      #pragma unroll
      for (int j = 0; j < WN; ++j) bfr[j] = *(const bf16x8*)(Bs + (wno + j*16 + row)*LDK + ks*32 + kq*8);
      #pragma unroll
      for (int i = 0; i < WM; ++i){
        #pragma unroll
        for (int j = 0; j < WN; ++j)
          acc[i][j] = __builtin_amdgcn_mfma_f32_16x16x32_bf16(af[i], bfr[j], acc[i][j], 0, 0, 0);
      }
    }
  }
  #pragma unroll
  for (int i = 0; i < WM; ++i){
    int cm = m0 + wmo + i*16 + kq*4;
    #pragma unroll
    for (int j = 0; j < WN; ++j){
      int cn = n0 + wno + j*16 + row;
      #pragma unroll
      for (int ii = 0; ii < 4; ++ii){
        size_t idx = (size_t)(cm + ii)*ldc + cn;
        float v = acc[i][j][ii];
        if (addsrc) v += addsrc[idx];
        C[idx] = (OutT)v;
      }
    }
  }
}

// ======== fused conv4+SiLU -> xproj MFMA (K-split) -> dt_proj+softplus ========
__global__ __launch_bounds__(256) void conv_xproj_dt_kernel(
  const __bf16* __restrict__ xz16, const float* __restrict__ cw, const float* __restrict__ cb,
  const __bf16* __restrict__ wxp, const float* __restrict__ dtw, const float* __restrict__ dtb,
  __bf16* __restrict__ u16, float* __restrict__ xdbl, __bf16* __restrict__ delta16)
{
  __shared__ __bf16 su[16][1032];     // rows 0..CBT-1 valid; +8 pad
  __shared__ float  sdt[CBT][17];
  __shared__ f32x4  spart[4][3][64];  // [kwave][tile][lane] partial xproj sums
  int tid = threadIdx.x;
  int m0 = blockIdx.x * CBT;
  // ---- phase A: causal depthwise conv4 + bias + SiLU (rolling 4-row register window) ----
  {
    int d = tid * 4;
    float w[4][4], bias[4];
    #pragma unroll
    for (int c = 0; c < 4; ++c){
      #pragma unroll
      for (int j = 0; j < 4; ++j) w[c][j] = cw[(d + c)*4 + j];
      bias[c] = cb[d + c];
    }
    bf16x4 zero4; zero4[0] = (__bf16)0.f; zero4[1] = (__bf16)0.f; zero4[2] = (__bf16)0.f; zero4[3] = (__bf16)0.f;
    bf16x4 rm3 = (m0 >= 3) ? *(const bf16x4*)(xz16 + (size_t)(m0-3)*2048 + d) : zero4;
    bf16x4 rm2 = (m0 >= 2) ? *(const bf16x4*)(xz16 + (size_t)(m0-2)*2048 + d) : zero4;
    bf16x4 rm1 = (m0 >= 1) ? *(const bf16x4*)(xz16 + (size_t)(m0-1)*2048 + d) : zero4;
    for (int ti = 0; ti < CBT; ++ti){
      int m = m0 + ti;
      bf16x4 cur = *(const bf16x4*)(xz16 + (size_t)m*2048 + d);
      float acc[4] = {0.f, 0.f, 0.f, 0.f};
      if (m < M_VALID){
        int b = m / L_WIN;
        int l = m - b*L_WIN;
        #pragma unroll
        for (int c = 0; c < 4; ++c) acc[c] = fmaf((float)cur[c], w[c][3], bias[c]);
        if (l >= 1){
          #pragma unroll
          for (int c = 0; c < 4; ++c) acc[c] = fmaf((float)rm1[c], w[c][2], acc[c]);
        }
        if (l >= 2){
          #pragma unroll
          for (int c = 0; c < 4; ++c) acc[c] = fmaf((float)rm2[c], w[c][1], acc[c]);
        }
        if (l >= 3){
          #pragma unroll
          for (int c = 0; c < 4; ++c) acc[c] = fmaf((float)rm3[c], w[c][0], acc[c]);
        }
        #pragma unroll
        for (int c = 0; c < 4; ++c) acc[c] = acc[c] * sigmoidf_(acc[c]);
      }
      bf16x4 o;
      #pragma unroll
      for (int c = 0; c < 4; ++c) o[c] = (__bf16)acc[c];
      *(bf16x4*)(u16 + (size_t)m*DI + d) = o;
      *(bf16x4*)(&su[ti][d]) = o;
      rm3 = rm2; rm2 = rm1; rm1 = cur;
    }
  }
  __syncthreads();
  // ---- phase B: xproj, CBT tokens x 48 outputs, K=1024 split across 4 waves ----
  {
    int lane = tid & 63, wv = tid >> 6;
    int row = lane & 15, kq = lane >> 4;
    int kbase = wv * 256;
    f32x4 acc0 = {0,0,0,0}, acc1 = {0,0,0,0}, acc2 = {0,0,0,0};
    const __bf16* B0 = wxp + (size_t)(row)*1024      + kbase + kq*8;
    const __bf16* B1 = wxp + (size_t)(16 + row)*1024 + kbase + kq*8;
    const __bf16* B2 = wxp + (size_t)(32 + row)*1024 + kbase + kq*8;
    #pragma unroll
    for (int k = 0; k < 256; k += 32){
      bf16x8 a = *(const bf16x8*)(&su[row][kbase + k + kq*8]);
      acc0 = __builtin_amdgcn_mfma_f32_16x16x32_bf16(a, *(const bf16x8*)(B0 + k), acc0, 0, 0, 0);
      acc1 = __builtin_amdgcn_mfma_f32_16x16x32_bf16(a, *(const bf16x8*)(B1 + k), acc1, 0, 0, 0);
      acc2 = __builtin_amdgcn_mfma_f32_16x16x32_bf16(a, *(const bf16x8*)(B2 + k), acc2, 0, 0, 0);
    }
    spart[wv][0][lane] = acc0;
    spart[wv][1][lane] = acc1;
    spart[wv][2][lane] = acc2;
  }
  __syncthreads();
  // ---- reduce partials, write xdbl + sdt (only valid tokens) ----
  if (tid < 192){
    int tno = tid >> 6, lane = tid & 63;
    int row = lane & 15, kq = lane >> 4;
    f32x4 sum = spart[0][tno][lane];
    sum += spart[1][tno][lane];
    sum += spart[2][tno][lane];
    sum += spart[3][tno][lane];
    #pragma unroll
    for (int i = 0; i < 4; ++i){
      int tok = kq*4 + i;
      if (tok < CBT){
        xdbl[(size_t)(m0 + tok)*48 + tno*16 + row] = sum[i];
        if (tno == 0) sdt[tok][row] = sum[i];
      }
    }
  }
  __syncthreads();
  // ---- phase C: dt_proj (K=16) + softplus -> delta16 ----
  {
    int d0 = tid * 4;
    float w[4][16], bias[4];
    #pragma unroll
    for (int c = 0; c < 4; ++c){
      #pragma unroll
      for (int q = 0; q < 16; ++q) w[c][q] = dtw[(d0 + c)*16 + q];
      bias[c] = dtb[d0 + c];
    }
    for (int t = 0; t < CBT; ++t){
      float acc[4] = {bias[0], bias[1], bias[2], bias[3]};
      #pragma unroll
      for (int r = 0; r < 16; ++r){
        float dv = sdt[t][r];
        #pragma unroll
        for (int c = 0; c < 4; ++c) acc[c] = fmaf(dv, w[c][r], acc[c]);
      }
      bf16x4 o;
      #pragma unroll
      for (int c = 0; c < 4; ++c) o[c] = (__bf16)softplusf_(acc[c]);
      *(bf16x4*)(delta16 + (size_t)(m0 + t)*DI + d0) = o;
    }
  }
}

// ================= chunked two-phase selective scan =================
__global__ __launch_bounds__(256) void scan_part1_kernel(
  const __bf16* __restrict__ u16, const __bf16* __restrict__ delta16,
  const float* __restrict__ xdbl, const float* __restrict__ Alog, float2* __restrict__ Pq)
{
  int bid = blockIdx.x;
  int s = bid & 15, dtile = (bid >> 4) & 63, b = bid >> 10;
  int d0 = dtile << 4;
  int tid = threadIdx.x;
  int c = tid >> 4, n = tid & 15;
  float A2 = -__expf(Alog[(d0 + c)*16 + n]) * LOG2E;   // exp(dlt*A) = exp2(dlt*A2)
  __shared__ float2 sdd[16][SEG+2];   // (dlt, dlt*u)
  __shared__ float  sB [SEG][17];
  int t0 = s*SEG;
  int nt = L_WIN - t0; if (nt > SEG) nt = SEG;
  size_t base_m = (size_t)b*L_WIN + t0;
  // ---- vectorized staging: delta/u rows (threads 0..127), B quarters (all) ----
  if (tid < 128){
    int row = tid >> 1, half = tid & 1;
    bf16x8 dl8, u8;
    if (row < nt){
      size_t m = base_m + row;
      dl8 = *(const bf16x8*)(delta16 + m*DI + d0 + half*8);
      u8  = *(const bf16x8*)(u16    + m*DI + d0 + half*8);
    } else {
      #pragma unroll
      for (int j = 0; j < 8; ++j){ dl8[j] = (__bf16)0.f; u8[j] = (__bf16)0.f; }
    }
    #pragma unroll
    for (int j = 0; j < 8; ++j){
      float dlt = (float)dl8[j];
      sdd[half*8 + j][row] = make_float2(dlt, dlt * (float)u8[j]);
    }
  }
  {
    int row = tid & 63, q = tid >> 6;
    f32x4 B4 = {0,0,0,0};
    if (row < nt) B4 = *(const f32x4*)(xdbl + (base_m + row)*48 + 16 + q*4);
    #pragma unroll
    for (int j = 0; j < 4; ++j) sB[row][q*4 + j] = B4[j];
  }
  __syncthreads();
  float h = 0.f, sd = 0.f;
  #pragma unroll 8
  for (int t = 0; t < SEG; ++t){
    float2 dd2 = sdd[c][t];
    float dA = exp2f(dd2.x * A2);
    h = fmaf(dA, h, dd2.y * sB[t][n]);
    sd += dd2.x;                        // P = exp2(A2 * sum(dlt)): one exp2 at end
  }
  float P = exp2f(sd * A2);
  Pq[(((size_t)b*NSEG + s) << 14) + (dtile << 8) + tid] = make_float2(P, h);
}

// r8: butterfly 4->3 steps (lanes n=0/n=8 write half-sums into sdd[c][t].x/.y,
// both dead — epilogue adds them; bit-identical to the dropped ror:8 add).
// Prefix widened 4->8 in flight (worst-case latency rounds 4->2; +8 VGPR, <64).
__global__ __launch_bounds__(256) void scan_part2_kernel(
  const __bf16* __restrict__ u16, const __bf16* __restrict__ delta16,
  const float* __restrict__ xdbl, const __bf16* __restrict__ xz16,
  const float* __restrict__ Alog, const float* __restrict__ Dp,
  const float2* __restrict__ Pq, __bf16* __restrict__ y16)
{
  int bid = blockIdx.x;
  int s = bid & 15, dtile = (bid >> 4) & 63, b = bid >> 10;
  int d0 = dtile << 4;
  int tid = threadIdx.x;
  int c = tid >> 4, n = tid & 15;
  float A2 = -__expf(Alog[(d0 + c)*16 + n]) * LOG2E;
  __shared__ float2 sdd[16][SEG+2];   // (dlt, dlt*u); becomes (y_lo, y_hi) after serial
  __shared__ float2 sBC[SEG][17];     // (B_n, C_n)
  __shared__ float  sD[16];
  if (tid < 16) sD[tid] = Dp[d0 + tid];
  int t0 = s*SEG;
  int nt = L_WIN - t0; if (nt > SEG) nt = SEG;
  size_t base_m = (size_t)b*L_WIN + t0;
  // ---- vectorized staging (issues before the prefix chain) ----
  if (tid < 128){
    int row = tid >> 1, half = tid & 1;
    bf16x8 dl8, u8;
    if (row < nt){
      size_t m = base_m + row;
      dl8 = *(const bf16x8*)(delta16 + m*DI + d0 + half*8);
      u8  = *(const bf16x8*)(u16    + m*DI + d0 + half*8);
    } else {
      #pragma unroll
      for (int j = 0; j < 8; ++j){ dl8[j] = (__bf16)0.f; u8[j] = (__bf16)0.f; }
    }
    #pragma unroll
    for (int j = 0; j < 8; ++j){
      float dlt = (float)dl8[j];
      sdd[half*8 + j][row] = make_float2(dlt, dlt * (float)u8[j]);
    }
  }
  {
    int row = tid & 63, q = tid >> 6;
    f32x4 B4 = {0,0,0,0}, C4 = {0,0,0,0};
    if (row < nt){
      size_t m = base_m + row;
      B4 = *(const f32x4*)(xdbl + m*48 + 16 + q*4);
      C4 = *(const f32x4*)(xdbl + m*48 + 32 + q*4);
    }
    #pragma unroll
    for (int j = 0; j < 4; ++j) sBC[row][q*4 + j] = make_float2(B4[j], C4[j]);
  }
  // ---- batched prefix over earlier segments' (P,q): 8 loads in flight ----
  float h = 0.f;
  {
    size_t pqbase = (((size_t)b*NSEG) << 14) + (dtile << 8) + tid;
    for (int s0 = 0; s0 < 15; s0 += 8){
      if (s0 >= s) break;               // wave-uniform
      float2 r[8];
      #pragma unroll
      for (int j = 0; j < 8; ++j)
        r[j] = Pq[pqbase + ((size_t)(s0 + j) << 14)];   // sp<=15 always valid memory
      #pragma unroll
      for (int j = 0; j < 8; ++j)
        if (s0 + j < s) h = fmaf(r[j].x, h, r[j].y);
    }
  }
  __syncthreads();
  // ---- serial chain + 3-step DPP reduce; half-sums land in sdd[c][t].x/.y ----
  bool wl = ((n & 7) == 0);
  int wslot = n >> 3;                   // 0 -> .x, 1 -> .y
  #pragma unroll 8
  for (int t = 0; t < SEG; ++t){
    float2 dd2 = sdd[c][t];
    float dA = exp2f(dd2.x * A2);
    float2 bc = sBC[t][n];
    h = fmaf(dA, h, dd2.y * bc.x);
    float pp = h * bc.y;
    pp = dpp_add<0xB1>(pp);    // xor1
    pp = dpp_add<0x4E>(pp);    // xor2
    pp = dpp_add<0x141>(pp);   // row_half_mirror -> half-group sums
    if (wl) ((float*)&sdd[c][t])[wslot] = pp;   // wave-private row (wave owns c)
  }
  __syncthreads();
  // ---- vectorized epilogue: threads 0..127, one half-row each ----
  if (tid < 128){
    int tt = tid >> 1, half = tid & 1;
    if (tt < nt){
      size_t m = base_m + tt;
      bf16x8 z8 = *(const bf16x8*)(xz16 + m*2048 + 1024 + d0 + half*8);
      bf16x8 u8 = *(const bf16x8*)(u16 + m*DI + d0 + half*8);
      bf16x8 o;
      #pragma unroll
      for (int j = 0; j < 8; ++j){
        int dd = half*8 + j;
        float2 yh = sdd[dd][tt];
        float zv = (float)z8[j];
        float yv = ((yh.x + yh.y) + (float)u8[j] * sD[dd]) * (zv * sigmoidf_(zv));
        o[j] = (__bf16)yv;
      }
      *(bf16x8*)(y16 + m*DI + d0 + half*8) = o;
    }
  }
}

// ---------------- overlap-add fold + passthrough ----------------
__global__ __launch_bounds__(256) void fold_kernel(const float* __restrict__ x, const float* __restrict__ r,
                                                   float* __restrict__ out){
  int i = blockIdx.x*256 + threadIdx.x;
  int b = i >> 17;
  int t = i & (TLEN - 1);
  float acc = x[i];
  int l1 = t >> 7;
  int j  = t & 127;
  if (l1 < L_WIN) acc += r[((size_t)b*L_WIN + l1)*DIMC + j] * ((float)j * (1.f/127.f));
  if (l1 >= 1)    acc += r[((size_t)b*L_WIN + l1 - 1)*DIMC + j + 128] * ((float)(127 - j) * (1.f/127.f));
  out[i] = acc;
}

extern "C" void kernel_launch(void* const* d_in, const int* in_sizes, int n_in,
                              void* d_out, int out_size, void* d_ws, size_t ws_size,
                              hipStream_t stream)
{
  (void)in_sizes; (void)n_in; (void)out_size; (void)ws_size;
  const float* x      = (const float*)d_in[0];
  const float* in_w   = (const float*)d_in[1];
  const float* conv_w = (const float*)d_in[2];
  const float* conv_b = (const float*)d_in[3];
  const float* xp_w   = (const float*)d_in[4];
  const float* dt_w   = (const float*)d_in[5];
  const float* dt_b   = (const float*)d_in[6];
  const float* A_log  = (const float*)d_in[7];
  const float* Dp     = (const float*)d_in[8];
  const float* out_w  = (const float*)d_in[9];
  const float* norm_w = (const float*)d_in[10];
  float* out = (float*)d_out;

  // workspace layout (~56 MB; ws is 256 MiB)
  char* p = (char*)d_ws;
  auto alloc = [&](size_t bytes)->void*{ void* r = (void*)p; p += (bytes + 255) & ~(size_t)255; return r; };
  float*  res    = (float*) alloc((size_t)M_PAD*DIMC*4);        // 4 MB
  __bf16* hn16   = (__bf16*)alloc((size_t)M_PAD*DIMC*2);        // 2 MB
  __bf16* xz16   = (__bf16*)alloc((size_t)M_PAD*2048*2);        // 16 MB
  __bf16* u16    = (__bf16*)alloc((size_t)M_PAD*DI*2);          // 8 MB
  float*  xdbl   = (float*) alloc((size_t)M_PAD*48*4);          // 0.75 MB
  __bf16* delta16= (__bf16*)alloc((size_t)M_PAD*DI*2);          // 8 MB
  __bf16* y16    = (__bf16*)alloc((size_t)M_PAD*DI*2);          // 8 MB
  float2* Pq     = (float2*)alloc((size_t)4*NSEG*16384*8);      // 8 MB
  __bf16* w_in16 = (__bf16*)alloc((size_t)2*2048*256*2);        // 2 MB
  __bf16* w_xp16 = (__bf16*)alloc((size_t)2*48*1024*2);         // 0.19 MB
  __bf16* w_out16= (__bf16*)alloc((size_t)2*256*1024*2);        // 1 MB

  init_kernel<<<M_PAD + 512, 256, 0, stream>>>(x, res, hn16, norm_w,
                                               in_w, w_in16, 2*2048*256,
                                               xp_w, w_xp16, 2*48*1024,
                                               out_w, w_out16, 2*256*1024);

  for (int i = 0; i < 2; ++i){
    if (i == 1)
      rms_kernel<<<M_PAD, 256, 0, stream>>>(res, hn16, norm_w + 256);
    // in_proj: M=4096 N=2048 K=256; 128x64 tile -> 1024 blocks = 4/CU
    gemm_tiled_kernel<4, 2, __bf16><<<dim3(32, 32), 256, 0, stream>>>(hn16, w_in16 + (size_t)i*524288, xz16, nullptr, 256, 2048);
    conv_xproj_dt_kernel<<<M_PAD/CBT, 256, 0, stream>>>(xz16, conv_w + i*4096, conv_b + i*1024,
                                                        w_xp16 + (size_t)i*49152, dt_w + i*16384, dt_b + i*1024,
                                                        u16, xdbl, delta16);
    scan_part1_kernel<<<4096, 256, 0, stream>>>(u16, delta16, xdbl, A_log + i*16384, Pq);
    scan_part2_kernel<<<4096, 256, 0, stream>>>(u16, delta16, xdbl, xz16, A_log + i*16384, Dp + i*1024,
                                                Pq, y16);
    // out_proj: M=4096 N=256 K=1024; 64x32 tile -> 512 blocks = 2/CU
    gemm_tiled_kernel<2, 1, float><<<dim3(64, 8), 256, 0, stream>>>(y16, w_out16 + (size_t)i*262144, res, res, 1024, 256);
  }
  fold_kernel<<<TLEN*4/256, 256, 0, stream>>>(x, res, out);
}

// Round 9
// 299.049 us; speedup vs baseline: 1.1709x; 1.0092x over previous
//
#include <hip/hip_runtime.h>
#include <cmath>

// ---- problem constants ----
#define DIMC   256
#define L_WIN  1023        // (131072-256)/128 + 1
#define M_VALID 4092       // 4*1023 tokens
#define M_PAD  4096
#define DI     1024        // D_INNER
#define TLEN   131072
#define SEG    64          // scan segment length
#define NSEG   16          // 16*64 = 1024 >= 1023
#define CBT    8           // tokens per conv_xproj block

typedef __bf16 bf16x8 __attribute__((ext_vector_type(8)));
typedef __bf16 bf16x4 __attribute__((ext_vector_type(4)));
typedef float  f32x4  __attribute__((ext_vector_type(4)));

#define LOG2E 1.4426950408889634f

__device__ __forceinline__ float sigmoidf_(float x){ return 1.f/(1.f + __expf(-x)); }
__device__ __forceinline__ float softplusf_(float v){ return fmaxf(v,0.f) + log1pf(__expf(-fabsf(v))); }

// DPP rotate-add: pure-VALU cross-lane sum step (no LDS traffic)
template<int CTRL>
__device__ __forceinline__ float dpp_add(float x){
  int v = __builtin_amdgcn_update_dpp(0, __builtin_bit_cast(int, x), CTRL, 0xF, 0xF, true);
  return x + __builtin_bit_cast(float, v);
}

// ---------------- init: frame + LAYER-0 RMSNORM (blocks 0..4095) + weight convert (4096+) ----------
__global__ __launch_bounds__(256) void init_kernel(const float* __restrict__ x, float* __restrict__ res,
    __bf16* __restrict__ hn16, const float* __restrict__ w0,
    const float* __restrict__ a, __bf16* __restrict__ da, int na,
    const float* __restrict__ b, __bf16* __restrict__ db, int nb,
    const float* __restrict__ c, __bf16* __restrict__ dc, int nc)
{
  if (blockIdx.x < M_PAD){
    int m = blockIdx.x, j = threadIdx.x;
    float v = 0.f;
    if (m < M_VALID){
      int bb = m / L_WIN, l = m - bb*L_WIN;
      v = x[(size_t)bb*TLEN + l*128 + j];
    }
    res[(size_t)m*DIMC + j] = v;
    // ---- layer-0 rms fused ----
    float s = v*v;
    #pragma unroll
    for (int off = 32; off; off >>= 1) s += __shfl_down(s, off);
    __shared__ float ls[4];
    if ((threadIdx.x & 63) == 0) ls[threadIdx.x >> 6] = s;
    __syncthreads();
    float tot = ls[0] + ls[1] + ls[2] + ls[3];
    float scale = rsqrtf(tot * (1.f/DIMC) + 1e-5f);
    hn16[(size_t)m*DIMC + j] = (__bf16)(v * scale * w0[j]);
    return;
  }
  int nblk = gridDim.x - M_PAD;
  int stride = nblk*256;
  int base = (blockIdx.x - M_PAD)*256 + threadIdx.x;
  for (int i = base; i < na; i += stride) da[i] = (__bf16)a[i];
  for (int i = base; i < nb; i += stride) db[i] = (__bf16)b[i];
  for (int i = base; i < nc; i += stride) dc[i] = (__bf16)c[i];
}

// ---------------- rmsnorm row of 256 -> bf16 (layer 1 only; layer 0 fused into init) ------------
__global__ __launch_bounds__(256) void rms_kernel(const float* __restrict__ src, __bf16* __restrict__ dst,
                                                  const float* __restrict__ w){
  int m = blockIdx.x, j = threadIdx.x;
  float v = (m < M_VALID) ? src[(size_t)m*DIMC + j] : 0.f;
  float s = v*v;
  #pragma unroll
  for (int off = 32; off; off >>= 1) s += __shfl_down(s, off);
  __shared__ float ls[4];
  if ((threadIdx.x & 63) == 0) ls[threadIdx.x >> 6] = s;
  __syncthreads();
  float tot = ls[0] + ls[1] + ls[2] + ls[3];
  float scale = rsqrtf(tot * (1.f/DIMC) + 1e-5f);
  dst[(size_t)m*DIMC + j] = (__bf16)(v * scale * w[j]);
}

// ======== LDS-tiled bf16 MFMA GEMM: C[M x N] = A[M x K] * B[N x K]^T (+addsrc) ========
// NOTE: C/addsrc NOT __restrict__ — out_proj call is in-place (C==addsrc).
template<int WM, int WN, typename OutT>
__global__ __launch_bounds__(256) void gemm_tiled_kernel(const __bf16* __restrict__ A, const __bf16* __restrict__ B,
    OutT* C, const float* addsrc, int K, int ldc)
{
  constexpr int BM  = 32*WM;
  constexpr int BN  = 32*WN;
  constexpr int LDK = 72;
  __shared__ __bf16 As[BM*LDK];
  __shared__ __bf16 Bs[BN*LDK];
  int tid  = threadIdx.x;
  int lane = tid & 63, wv = tid >> 6;
  int row  = lane & 15, kq = lane >> 4;
  int m0 = blockIdx.x*BM, n0 = blockIdx.y*BN;
  int wmo = (wv >> 1)*(16*WM);
  int wno = (wv &  1)*(16*WN);
  f32x4 acc[WM][WN] = {};
  for (int kt = 0; kt < K; kt += 64){
    __syncthreads();
    #pragma unroll
    for (int r = 0; r < BM/32; ++r){
      int seg = r*256 + tid;
      int rw = seg >> 3, sb = seg & 7;
      *(bf16x8*)(As + rw*LDK + sb*8) = *(const bf16x8*)(A + (size_t)(m0 + rw)*K + kt + sb*8);
    }
    #pragma unroll
    for (int r = 0; r < BN/32; ++r){
      int seg = r*256 + tid;
      int rw = seg >> 3, sb = seg & 7;
      *(bf16x8*)(Bs + rw*LDK + sb*8) = *(const bf16x8*)(B + (size_t)(n0 + rw)*K + kt + sb*8);
    }
    __syncthreads();
    #pragma unroll
    for (int ks = 0; ks < 2; ++ks){
      bf16x8 af[WM], bfr[WN];
      #pragma unroll
      for (int i = 0; i < WM; ++i) af[i]  = *(const bf16x8*)(As + (wmo + i*16 + row)*LDK + ks*32 + kq*8);
      #pragma unroll
      for (int j = 0; j < WN; ++j) bfr[j] = *(const bf16x8*)(Bs + (wno + j*16 + row)*LDK + ks*32 + kq*8);
      #pragma unroll
      for (int i = 0; i < WM; ++i){
        #pragma unroll
        for (int j = 0; j < WN; ++j)
          acc[i][j] = __builtin_amdgcn_mfma_f32_16x16x32_bf16(af[i], bfr[j], acc[i][j], 0, 0, 0);
      }
    }
  }
  #pragma unroll
  for (int i = 0; i < WM; ++i){
    int cm = m0 + wmo + i*16 + kq*4;
    #pragma unroll
    for (int j = 0; j < WN; ++j){
      int cn = n0 + wno + j*16 + row;
      #pragma unroll
      for (int ii = 0; ii < 4; ++ii){
        size_t idx = (size_t)(cm + ii)*ldc + cn;
        float v = acc[i][j][ii];
        if (addsrc) v += addsrc[idx];
        C[idx] = (OutT)v;
      }
    }
  }
}

// ======== fused conv4+SiLU -> xproj MFMA (K-split) -> dt_proj+softplus ========
__global__ __launch_bounds__(256) void conv_xproj_dt_kernel(
  const __bf16* __restrict__ xz16, const float* __restrict__ cw, const float* __restrict__ cb,
  const __bf16* __restrict__ wxp, const float* __restrict__ dtw, const float* __restrict__ dtb,
  __bf16* __restrict__ u16, float* __restrict__ xdbl, __bf16* __restrict__ delta16)
{
  __shared__ __bf16 su[16][1032];     // rows 0..CBT-1 valid; +8 pad
  __shared__ float  sdt[CBT][17];
  __shared__ f32x4  spart[4][3][64];  // [kwave][tile][lane] partial xproj sums
  int tid = threadIdx.x;
  int m0 = blockIdx.x * CBT;
  // ---- phase A: causal depthwise conv4 + bias + SiLU (rolling 4-row register window) ----
  {
    int d = tid * 4;
    float w[4][4], bias[4];
    #pragma unroll
    for (int c = 0; c < 4; ++c){
      #pragma unroll
      for (int j = 0; j < 4; ++j) w[c][j] = cw[(d + c)*4 + j];
      bias[c] = cb[d + c];
    }
    bf16x4 zero4; zero4[0] = (__bf16)0.f; zero4[1] = (__bf16)0.f; zero4[2] = (__bf16)0.f; zero4[3] = (__bf16)0.f;
    bf16x4 rm3 = (m0 >= 3) ? *(const bf16x4*)(xz16 + (size_t)(m0-3)*2048 + d) : zero4;
    bf16x4 rm2 = (m0 >= 2) ? *(const bf16x4*)(xz16 + (size_t)(m0-2)*2048 + d) : zero4;
    bf16x4 rm1 = (m0 >= 1) ? *(const bf16x4*)(xz16 + (size_t)(m0-1)*2048 + d) : zero4;
    for (int ti = 0; ti < CBT; ++ti){
      int m = m0 + ti;
      bf16x4 cur = *(const bf16x4*)(xz16 + (size_t)m*2048 + d);
      float acc[4] = {0.f, 0.f, 0.f, 0.f};
      if (m < M_VALID){
        int b = m / L_WIN;
        int l = m - b*L_WIN;
        #pragma unroll
        for (int c = 0; c < 4; ++c) acc[c] = fmaf((float)cur[c], w[c][3], bias[c]);
        if (l >= 1){
          #pragma unroll
          for (int c = 0; c < 4; ++c) acc[c] = fmaf((float)rm1[c], w[c][2], acc[c]);
        }
        if (l >= 2){
          #pragma unroll
          for (int c = 0; c < 4; ++c) acc[c] = fmaf((float)rm2[c], w[c][1], acc[c]);
        }
        if (l >= 3){
          #pragma unroll
          for (int c = 0; c < 4; ++c) acc[c] = fmaf((float)rm3[c], w[c][0], acc[c]);
        }
        #pragma unroll
        for (int c = 0; c < 4; ++c) acc[c] = acc[c] * sigmoidf_(acc[c]);
      }
      bf16x4 o;
      #pragma unroll
      for (int c = 0; c < 4; ++c) o[c] = (__bf16)acc[c];
      *(bf16x4*)(u16 + (size_t)m*DI + d) = o;
      *(bf16x4*)(&su[ti][d]) = o;
      rm3 = rm2; rm2 = rm1; rm1 = cur;
    }
  }
  __syncthreads();
  // ---- phase B: xproj, CBT tokens x 48 outputs, K=1024 split across 4 waves ----
  {
    int lane = tid & 63, wv = tid >> 6;
    int row = lane & 15, kq = lane >> 4;
    int kbase = wv * 256;
    f32x4 acc0 = {0,0,0,0}, acc1 = {0,0,0,0}, acc2 = {0,0,0,0};
    const __bf16* B0 = wxp + (size_t)(row)*1024      + kbase + kq*8;
    const __bf16* B1 = wxp + (size_t)(16 + row)*1024 + kbase + kq*8;
    const __bf16* B2 = wxp + (size_t)(32 + row)*1024 + kbase + kq*8;
    #pragma unroll
    for (int k = 0; k < 256; k += 32){
      bf16x8 a = *(const bf16x8*)(&su[row][kbase + k + kq*8]);
      acc0 = __builtin_amdgcn_mfma_f32_16x16x32_bf16(a, *(const bf16x8*)(B0 + k), acc0, 0, 0, 0);
      acc1 = __builtin_amdgcn_mfma_f32_16x16x32_bf16(a, *(const bf16x8*)(B1 + k), acc1, 0, 0, 0);
      acc2 = __builtin_amdgcn_mfma_f32_16x16x32_bf16(a, *(const bf16x8*)(B2 + k), acc2, 0, 0, 0);
    }
    spart[wv][0][lane] = acc0;
    spart[wv][1][lane] = acc1;
    spart[wv][2][lane] = acc2;
  }
  __syncthreads();
  // ---- reduce partials, write xdbl + sdt (only valid tokens) ----
  if (tid < 192){
    int tno = tid >> 6, lane = tid & 63;
    int row = lane & 15, kq = lane >> 4;
    f32x4 sum = spart[0][tno][lane];
    sum += spart[1][tno][lane];
    sum += spart[2][tno][lane];
    sum += spart[3][tno][lane];
    #pragma unroll
    for (int i = 0; i < 4; ++i){
      int tok = kq*4 + i;
      if (tok < CBT){
        xdbl[(size_t)(m0 + tok)*48 + tno*16 + row] = sum[i];
        if (tno == 0) sdt[tok][row] = sum[i];
      }
    }
  }
  __syncthreads();
  // ---- phase C: dt_proj (K=16) + softplus -> delta16 ----
  {
    int d0 = tid * 4;
    float w[4][16], bias[4];
    #pragma unroll
    for (int c = 0; c < 4; ++c){
      #pragma unroll
      for (int q = 0; q < 16; ++q) w[c][q] = dtw[(d0 + c)*16 + q];
      bias[c] = dtb[d0 + c];
    }
    for (int t = 0; t < CBT; ++t){
      float acc[4] = {bias[0], bias[1], bias[2], bias[3]};
      #pragma unroll
      for (int r = 0; r < 16; ++r){
        float dv = sdt[t][r];
        #pragma unroll
        for (int c = 0; c < 4; ++c) acc[c] = fmaf(dv, w[c][r], acc[c]);
      }
      bf16x4 o;
      #pragma unroll
      for (int c = 0; c < 4; ++c) o[c] = (__bf16)softplusf_(acc[c]);
      *(bf16x4*)(delta16 + (size_t)(m0 + t)*DI + d0) = o;
    }
  }
}

// ================= chunked two-phase selective scan =================
__global__ __launch_bounds__(256) void scan_part1_kernel(
  const __bf16* __restrict__ u16, const __bf16* __restrict__ delta16,
  const float* __restrict__ xdbl, const float* __restrict__ Alog, float2* __restrict__ Pq)
{
  int bid = blockIdx.x;
  int s = bid & 15, dtile = (bid >> 4) & 63, b = bid >> 10;
  if (s == 15) return;   // r9: (P,h) of the last segment is never read (prefix uses sp<s<=15)
  int d0 = dtile << 4;
  int tid = threadIdx.x;
  int c = tid >> 4, n = tid & 15;
  float A2 = -__expf(Alog[(d0 + c)*16 + n]) * LOG2E;   // exp(dlt*A) = exp2(dlt*A2)
  __shared__ float2 sdd[16][SEG+2];   // (dlt, dlt*u)
  __shared__ float  sB [SEG][17];
  int t0 = s*SEG;
  int nt = L_WIN - t0; if (nt > SEG) nt = SEG;
  size_t base_m = (size_t)b*L_WIN + t0;
  // ---- vectorized staging: delta/u rows (threads 0..127), B quarters (all) ----
  if (tid < 128){
    int row = tid >> 1, half = tid & 1;
    bf16x8 dl8, u8;
    if (row < nt){
      size_t m = base_m + row;
      dl8 = *(const bf16x8*)(delta16 + m*DI + d0 + half*8);
      u8  = *(const bf16x8*)(u16    + m*DI + d0 + half*8);
    } else {
      #pragma unroll
      for (int j = 0; j < 8; ++j){ dl8[j] = (__bf16)0.f; u8[j] = (__bf16)0.f; }
    }
    #pragma unroll
    for (int j = 0; j < 8; ++j){
      float dlt = (float)dl8[j];
      sdd[half*8 + j][row] = make_float2(dlt, dlt * (float)u8[j]);
    }
  }
  {
    int row = tid & 63, q = tid >> 6;
    f32x4 B4 = {0,0,0,0};
    if (row < nt) B4 = *(const f32x4*)(xdbl + (base_m + row)*48 + 16 + q*4);
    #pragma unroll
    for (int j = 0; j < 4; ++j) sB[row][q*4 + j] = B4[j];
  }
  __syncthreads();
  float h = 0.f, sd = 0.f;
  #pragma unroll 8
  for (int t = 0; t < SEG; ++t){
    float2 dd2 = sdd[c][t];
    float dA = exp2f(dd2.x * A2);
    h = fmaf(dA, h, dd2.y * sB[t][n]);
    sd += dd2.x;                        // P = exp2(A2 * sum(dlt)): one exp2 at end
  }
  float P = exp2f(sd * A2);
  Pq[(((size_t)b*NSEG + s) << 14) + (dtile << 8) + tid] = make_float2(P, h);
}

__global__ __launch_bounds__(256) void scan_part2_kernel(
  const __bf16* __restrict__ u16, const __bf16* __restrict__ delta16,
  const float* __restrict__ xdbl, const __bf16* __restrict__ xz16,
  const float* __restrict__ Alog, const float* __restrict__ Dp,
  const float2* __restrict__ Pq, __bf16* __restrict__ y16)
{
  int bid = blockIdx.x;
  int s = bid & 15, dtile = (bid >> 4) & 63, b = bid >> 10;
  int d0 = dtile << 4;
  int tid = threadIdx.x;
  int c = tid >> 4, n = tid & 15;
  float A2 = -__expf(Alog[(d0 + c)*16 + n]) * LOG2E;
  __shared__ float2 sdd[16][SEG+2];   // (dlt, dlt*u); becomes (y_lo, y_hi) after serial
  __shared__ float2 sBC[SEG][17];     // (B_n, C_n)
  __shared__ float  sD[16];
  if (tid < 16) sD[tid] = Dp[d0 + tid];
  int t0 = s*SEG;
  int nt = L_WIN - t0; if (nt > SEG) nt = SEG;
  size_t base_m = (size_t)b*L_WIN + t0;
  // ---- vectorized staging (issues before the prefix chain) ----
  if (tid < 128){
    int row = tid >> 1, half = tid & 1;
    bf16x8 dl8, u8;
    if (row < nt){
      size_t m = base_m + row;
      dl8 = *(const bf16x8*)(delta16 + m*DI + d0 + half*8);
      u8  = *(const bf16x8*)(u16    + m*DI + d0 + half*8);
    } else {
      #pragma unroll
      for (int j = 0; j < 8; ++j){ dl8[j] = (__bf16)0.f; u8[j] = (__bf16)0.f; }
    }
    #pragma unroll
    for (int j = 0; j < 8; ++j){
      float dlt = (float)dl8[j];
      sdd[half*8 + j][row] = make_float2(dlt, dlt * (float)u8[j]);
    }
  }
  {
    int row = tid & 63, q = tid >> 6;
    f32x4 B4 = {0,0,0,0}, C4 = {0,0,0,0};
    if (row < nt){
      size_t m = base_m + row;
      B4 = *(const f32x4*)(xdbl + m*48 + 16 + q*4);
      C4 = *(const f32x4*)(xdbl + m*48 + 32 + q*4);
    }
    #pragma unroll
    for (int j = 0; j < 4; ++j) sBC[row][q*4 + j] = make_float2(B4[j], C4[j]);
  }
  // ---- batched prefix over earlier segments' (P,q): 8 loads in flight ----
  float h = 0.f;
  {
    size_t pqbase = (((size_t)b*NSEG) << 14) + (dtile << 8) + tid;
    for (int s0 = 0; s0 < 15; s0 += 8){
      if (s0 >= s) break;               // wave-uniform
      float2 r[8];
      #pragma unroll
      for (int j = 0; j < 8; ++j)
        r[j] = Pq[pqbase + ((size_t)(s0 + j) << 14)];   // sp<=14 slots always valid memory
      #pragma unroll
      for (int j = 0; j < 8; ++j)
        if (s0 + j < s) h = fmaf(r[j].x, h, r[j].y);
    }
  }
  __syncthreads();
  // ---- serial chain + 3-step DPP reduce; half-sums land in sdd[c][t].x/.y ----
  bool wl = ((n & 7) == 0);
  int wslot = n >> 3;                   // 0 -> .x, 1 -> .y
  #pragma unroll 8
  for (int t = 0; t < SEG; ++t){
    float2 dd2 = sdd[c][t];
    float dA = exp2f(dd2.x * A2);
    float2 bc = sBC[t][n];
    h = fmaf(dA, h, dd2.y * bc.x);
    float pp = h * bc.y;
    pp = dpp_add<0xB1>(pp);    // xor1
    pp = dpp_add<0x4E>(pp);    // xor2
    pp = dpp_add<0x141>(pp);   // row_half_mirror -> half-group sums
    if (wl) ((float*)&sdd[c][t])[wslot] = pp;   // wave-private row (wave owns c)
  }
  __syncthreads();
  // ---- vectorized epilogue: threads 0..127, one half-row each ----
  if (tid < 128){
    int tt = tid >> 1, half = tid & 1;
    if (tt < nt){
      size_t m = base_m + tt;
      bf16x8 z8 = *(const bf16x8*)(xz16 + m*2048 + 1024 + d0 + half*8);
      bf16x8 u8 = *(const bf16x8*)(u16 + m*DI + d0 + half*8);
      bf16x8 o;
      #pragma unroll
      for (int j = 0; j < 8; ++j){
        int dd = half*8 + j;
        float2 yh = sdd[dd][tt];
        float zv = (float)z8[j];
        float yv = ((yh.x + yh.y) + (float)u8[j] * sD[dd]) * (zv * sigmoidf_(zv));
        o[j] = (__bf16)yv;
      }
      *(bf16x8*)(y16 + m*DI + d0 + half*8) = o;
    }
  }
}

// ---------------- overlap-add fold + passthrough ----------------
__global__ __launch_bounds__(256) void fold_kernel(const float* __restrict__ x, const float* __restrict__ r,
                                                   float* __restrict__ out){
  int i = blockIdx.x*256 + threadIdx.x;
  int b = i >> 17;
  int t = i & (TLEN - 1);
  float acc = x[i];
  int l1 = t >> 7;
  int j  = t & 127;
  if (l1 < L_WIN) acc += r[((size_t)b*L_WIN + l1)*DIMC + j] * ((float)j * (1.f/127.f));
  if (l1 >= 1)    acc += r[((size_t)b*L_WIN + l1 - 1)*DIMC + j + 128] * ((float)(127 - j) * (1.f/127.f));
  out[i] = acc;
}

extern "C" void kernel_launch(void* const* d_in, const int* in_sizes, int n_in,
                              void* d_out, int out_size, void* d_ws, size_t ws_size,
                              hipStream_t stream)
{
  (void)in_sizes; (void)n_in; (void)out_size; (void)ws_size;
  const float* x      = (const float*)d_in[0];
  const float* in_w   = (const float*)d_in[1];
  const float* conv_w = (const float*)d_in[2];
  const float* conv_b = (const float*)d_in[3];
  const float* xp_w   = (const float*)d_in[4];
  const float* dt_w   = (const float*)d_in[5];
  const float* dt_b   = (const float*)d_in[6];
  const float* A_log  = (const float*)d_in[7];
  const float* Dp     = (const float*)d_in[8];
  const float* out_w  = (const float*)d_in[9];
  const float* norm_w = (const float*)d_in[10];
  float* out = (float*)d_out;

  // workspace layout (~56 MB; ws is 256 MiB)
  char* p = (char*)d_ws;
  auto alloc = [&](size_t bytes)->void*{ void* r = (void*)p; p += (bytes + 255) & ~(size_t)255; return r; };
  float*  res    = (float*) alloc((size_t)M_PAD*DIMC*4);        // 4 MB
  __bf16* hn16   = (__bf16*)alloc((size_t)M_PAD*DIMC*2);        // 2 MB
  __bf16* xz16   = (__bf16*)alloc((size_t)M_PAD*2048*2);        // 16 MB
  __bf16* u16    = (__bf16*)alloc((size_t)M_PAD*DI*2);          // 8 MB
  float*  xdbl   = (float*) alloc((size_t)M_PAD*48*4);          // 0.75 MB
  __bf16* delta16= (__bf16*)alloc((size_t)M_PAD*DI*2);          // 8 MB
  __bf16* y16    = (__bf16*)alloc((size_t)M_PAD*DI*2);          // 8 MB
  float2* Pq     = (float2*)alloc((size_t)4*NSEG*16384*8);      // 8 MB
  __bf16* w_in16 = (__bf16*)alloc((size_t)2*2048*256*2);        // 2 MB
  __bf16* w_xp16 = (__bf16*)alloc((size_t)2*48*1024*2);         // 0.19 MB
  __bf16* w_out16= (__bf16*)alloc((size_t)2*256*1024*2);        // 1 MB

  init_kernel<<<M_PAD + 512, 256, 0, stream>>>(x, res, hn16, norm_w,
                                               in_w, w_in16, 2*2048*256,
                                               xp_w, w_xp16, 2*48*1024,
                                               out_w, w_out16, 2*256*1024);

  for (int i = 0; i < 2; ++i){
    if (i == 1)
      rms_kernel<<<M_PAD, 256, 0, stream>>>(res, hn16, norm_w + 256);
    // in_proj: M=4096 N=2048 K=256; 128x64 tile -> 1024 blocks = 4/CU
    gemm_tiled_kernel<4, 2, __bf16><<<dim3(32, 32), 256, 0, stream>>>(hn16, w_in16 + (size_t)i*524288, xz16, nullptr, 256, 2048);
    conv_xproj_dt_kernel<<<M_PAD/CBT, 256, 0, stream>>>(xz16, conv_w + i*4096, conv_b + i*1024,
                                                        w_xp16 + (size_t)i*49152, dt_w + i*16384, dt_b + i*1024,
                                                        u16, xdbl, delta16);
    scan_part1_kernel<<<4096, 256, 0, stream>>>(u16, delta16, xdbl, A_log + i*16384, Pq);
    scan_part2_kernel<<<4096, 256, 0, stream>>>(u16, delta16, xdbl, xz16, A_log + i*16384, Dp + i*1024,
                                                Pq, y16);
    // out_proj: M=4096 N=256 K=1024; 32x32 tile -> 1024 blocks = 4/CU (r9: was 64x32, 2/CU)
    gemm_tiled_kernel<1, 1, float><<<dim3(128, 8), 256, 0, stream>>>(y16, w_out16 + (size_t)i*262144, res, res, 1024, 256);
  }
  fold_kernel<<<TLEN*4/256, 256, 0, stream>>>(x, res, out);
}

// Round 10
// 296.203 us; speedup vs baseline: 1.1822x; 1.0096x over previous
//
#include <hip/hip_runtime.h>
#include <cmath>

// ---- problem constants ----
#define DIMC   256
#define L_WIN  1023        // (131072-256)/128 + 1
#define M_VALID 4092       // 4*1023 tokens
#define M_PAD  4096
#define DI     1024        // D_INNER
#define TLEN   131072
#define SEG    64          // scan segment length
#define NSEG   16          // 16*64 = 1024 >= 1023
#define CBT    8           // tokens per conv_xproj block

typedef __bf16 bf16x8 __attribute__((ext_vector_type(8)));
typedef __bf16 bf16x4 __attribute__((ext_vector_type(4)));
typedef float  f32x4  __attribute__((ext_vector_type(4)));

#define LOG2E 1.4426950408889634f

__device__ __forceinline__ float sigmoidf_(float x){ return 1.f/(1.f + __expf(-x)); }
__device__ __forceinline__ float softplusf_(float v){ return fmaxf(v,0.f) + log1pf(__expf(-fabsf(v))); }

// DPP rotate-add: pure-VALU cross-lane sum step (no LDS traffic)
template<int CTRL>
__device__ __forceinline__ float dpp_add(float x){
  int v = __builtin_amdgcn_update_dpp(0, __builtin_bit_cast(int, x), CTRL, 0xF, 0xF, true);
  return x + __builtin_bit_cast(float, v);
}

// ---------------- init: frame + LAYER-0 RMSNORM (blocks 0..4095) + weight convert + rowsum zero ----
__global__ __launch_bounds__(256) void init_kernel(const float* __restrict__ x, float* __restrict__ res,
    __bf16* __restrict__ hn16, const float* __restrict__ w0, float* __restrict__ rowsum,
    const float* __restrict__ a, __bf16* __restrict__ da, int na,
    const float* __restrict__ b, __bf16* __restrict__ db, int nb,
    const float* __restrict__ c, __bf16* __restrict__ dc, int nc)
{
  if (blockIdx.x < M_PAD){
    int m = blockIdx.x, j = threadIdx.x;
    float v = 0.f;
    if (m < M_VALID){
      int bb = m / L_WIN, l = m - bb*L_WIN;
      v = x[(size_t)bb*TLEN + l*128 + j];
    }
    res[(size_t)m*DIMC + j] = v;
    // ---- layer-0 rms fused ----
    float s = v*v;
    #pragma unroll
    for (int off = 32; off; off >>= 1) s += __shfl_down(s, off);
    __shared__ float ls[4];
    if ((threadIdx.x & 63) == 0) ls[threadIdx.x >> 6] = s;
    __syncthreads();
    float tot = ls[0] + ls[1] + ls[2] + ls[3];
    float scale = rsqrtf(tot * (1.f/DIMC) + 1e-5f);
    hn16[(size_t)m*DIMC + j] = (__bf16)(v * scale * w0[j]);
    return;
  }
  int nblk = gridDim.x - M_PAD;
  int stride = nblk*256;
  int base = (blockIdx.x - M_PAD)*256 + threadIdx.x;
  for (int i = base; i < M_PAD; i += stride) rowsum[i] = 0.f;   // r10: for out_proj atomic rms
  for (int i = base; i < na; i += stride) da[i] = (__bf16)a[i];
  for (int i = base; i < nb; i += stride) db[i] = (__bf16)b[i];
  for (int i = base; i < nc; i += stride) dc[i] = (__bf16)c[i];
}

// ======== LDS-tiled bf16 MFMA GEMM: C[M x N] = A[M x K] * B[N x K]^T (+addsrc) ========
// NOTE: C/addsrc NOT __restrict__ — out_proj call is in-place (C==addsrc).
// r10: optional rowsum_out — epilogue DPP-reduces v^2 per row and atomicAdds
// (feeds the next layer's rms without a separate kernel or sum recompute).
template<int WM, int WN, typename OutT>
__global__ __launch_bounds__(256) void gemm_tiled_kernel(const __bf16* __restrict__ A, const __bf16* __restrict__ B,
    OutT* C, const float* addsrc, float* rowsum_out, int K, int ldc)
{
  constexpr int BM  = 32*WM;
  constexpr int BN  = 32*WN;
  constexpr int LDK = 72;
  __shared__ __bf16 As[BM*LDK];
  __shared__ __bf16 Bs[BN*LDK];
  int tid  = threadIdx.x;
  int lane = tid & 63, wv = tid >> 6;
  int row  = lane & 15, kq = lane >> 4;
  int m0 = blockIdx.x*BM, n0 = blockIdx.y*BN;
  int wmo = (wv >> 1)*(16*WM);
  int wno = (wv &  1)*(16*WN);
  f32x4 acc[WM][WN] = {};
  for (int kt = 0; kt < K; kt += 64){
    __syncthreads();
    #pragma unroll
    for (int r = 0; r < BM/32; ++r){
      int seg = r*256 + tid;
      int rw = seg >> 3, sb = seg & 7;
      *(bf16x8*)(As + rw*LDK + sb*8) = *(const bf16x8*)(A + (size_t)(m0 + rw)*K + kt + sb*8);
    }
    #pragma unroll
    for (int r = 0; r < BN/32; ++r){
      int seg = r*256 + tid;
      int rw = seg >> 3, sb = seg & 7;
      *(bf16x8*)(Bs + rw*LDK + sb*8) = *(const bf16x8*)(B + (size_t)(n0 + rw)*K + kt + sb*8);
    }
    __syncthreads();
    #pragma unroll
    for (int ks = 0; ks < 2; ++ks){
      bf16x8 af[WM], bfr[WN];
      #pragma unroll
      for (int i = 0; i < WM; ++i) af[i]  = *(const bf16x8*)(As + (wmo + i*16 + row)*LDK + ks*32 + kq*8);
      #pragma unroll
      for (int j = 0; j < WN; ++j) bfr[j] = *(const bf16x8*)(Bs + (wno + j*16 + row)*LDK + ks*32 + kq*8);
      #pragma unroll
      for (int i = 0; i < WM; ++i){
        #pragma unroll
        for (int j = 0; j < WN; ++j)
          acc[i][j] = __builtin_amdgcn_mfma_f32_16x16x32_bf16(af[i], bfr[j], acc[i][j], 0, 0, 0);
      }
    }
  }
  #pragma unroll
  for (int i = 0; i < WM; ++i){
    int cm = m0 + wmo + i*16 + kq*4;
    #pragma unroll
    for (int ii = 0; ii < 4; ++ii){
      float sq = 0.f;
      #pragma unroll
      for (int j = 0; j < WN; ++j){
        int cn = n0 + wno + j*16 + row;
        size_t idx = (size_t)(cm + ii)*ldc + cn;
        float v = acc[i][j][ii];
        if (addsrc) v += addsrc[idx];
        C[idx] = (OutT)v;
        sq += v*v;
      }
      if (rowsum_out){
        sq = dpp_add<0xB1>(sq);
        sq = dpp_add<0x4E>(sq);
        sq = dpp_add<0x141>(sq);
        sq = dpp_add<0x128>(sq);      // sum over the 16-lane (col) group
        if (row == 0) atomicAdd(rowsum_out + cm + ii, sq);
      }
    }
  }
}

// ======== fused rms + in_proj GEMM (layer 1): scale from PRE-ACCUMULATED rowsum ========
// r2's failure was each block recomputing row sums (32-load serial chain, x16
// redundant). Here scale = one rowsum load + rsqrt per row; A staged from fp32
// res with scale*w applied. Pad rows forced to 0 (conv relies on zero pads).
__global__ __launch_bounds__(256) void gemm_rms2_kernel(const float* __restrict__ Araw,
    const __bf16* __restrict__ B, const float* __restrict__ rowsum, const float* __restrict__ wn,
    __bf16* __restrict__ C, int ldc)
{
  constexpr int WM = 4, WN = 2;
  constexpr int BM = 128, BN = 64, LDK = 72;
  __shared__ __bf16 As[BM*LDK];
  __shared__ __bf16 Bs[BN*LDK];
  __shared__ float  sscale[BM];
  __shared__ float  swn[256];
  int tid  = threadIdx.x;
  int lane = tid & 63, wv = tid >> 6;
  int row  = lane & 15, kq = lane >> 4;
  int m0 = blockIdx.x*BM, n0 = blockIdx.y*BN;
  int wmo = (wv >> 1)*(16*WM);
  int wno = (wv &  1)*(16*WN);
  swn[tid] = wn[tid];
  if (tid < BM){
    int gr = m0 + tid;
    sscale[tid] = (gr < M_VALID) ? rsqrtf(rowsum[gr]*(1.f/DIMC) + 1e-5f) : 0.f;
  }
  f32x4 acc[WM][WN] = {};
  for (int kt = 0; kt < 256; kt += 64){
    __syncthreads();   // first pass also publishes sscale/swn
    #pragma unroll
    for (int r2 = 0; r2 < BM/32; ++r2){
      int seg = r2*256 + tid;
      int rw = seg >> 3, sb = seg & 7;
      int gr = m0 + rw;
      float sc = sscale[rw];
      f32x4 v0 = {0,0,0,0}, v1 = {0,0,0,0};
      if (gr < M_VALID){
        const float* ap = Araw + (size_t)gr*DIMC + kt + sb*8;
        v0 = *(const f32x4*)ap; v1 = *(const f32x4*)(ap + 4);
      }
      bf16x8 o;
      #pragma unroll
      for (int j = 0; j < 4; ++j){
        o[j]   = (__bf16)(v0[j] * sc * swn[kt + sb*8 + j]);
        o[4+j] = (__bf16)(v1[j] * sc * swn[kt + sb*8 + 4 + j]);
      }
      *(bf16x8*)(As + rw*LDK + sb*8) = o;
    }
    #pragma unroll
    for (int r2 = 0; r2 < BN/32; ++r2){
      int seg = r2*256 + tid;
      int rw = seg >> 3, sb = seg & 7;
      *(bf16x8*)(Bs + rw*LDK + sb*8) = *(const bf16x8*)(B + (size_t)(n0 + rw)*256 + kt + sb*8);
    }
    __syncthreads();
    #pragma unroll
    for (int ks = 0; ks < 2; ++ks){
      bf16x8 af[WM], bfr[WN];
      #pragma unroll
      for (int i = 0; i < WM; ++i) af[i]  = *(const bf16x8*)(As + (wmo + i*16 + row)*LDK + ks*32 + kq*8);
      #pragma unroll
      for (int j = 0; j < WN; ++j) bfr[j] = *(const bf16x8*)(Bs + (wno + j*16 + row)*LDK + ks*32 + kq*8);
      #pragma unroll
      for (int i = 0; i < WM; ++i){
        #pragma unroll
        for (int j = 0; j < WN; ++j)
          acc[i][j] = __builtin_amdgcn_mfma_f32_16x16x32_bf16(af[i], bfr[j], acc[i][j], 0, 0, 0);
      }
    }
  }
  #pragma unroll
  for (int i = 0; i < WM; ++i){
    int cm = m0 + wmo + i*16 + kq*4;
    #pragma unroll
    for (int j = 0; j < WN; ++j){
      int cn = n0 + wno + j*16 + row;
      #pragma unroll
      for (int ii = 0; ii < 4; ++ii)
        C[(size_t)(cm + ii)*ldc + cn] = (__bf16)acc[i][j][ii];
    }
  }
}

// ======== fused conv4+SiLU -> xproj MFMA (K-split) -> dt_proj+softplus ========
__global__ __launch_bounds__(256) void conv_xproj_dt_kernel(
  const __bf16* __restrict__ xz16, const float* __restrict__ cw, const float* __restrict__ cb,
  const __bf16* __restrict__ wxp, const float* __restrict__ dtw, const float* __restrict__ dtb,
  __bf16* __restrict__ u16, float* __restrict__ xdbl, __bf16* __restrict__ delta16)
{
  __shared__ __bf16 su[16][1032];     // rows 0..CBT-1 valid; +8 pad
  __shared__ float  sdt[CBT][17];
  __shared__ f32x4  spart[4][3][64];  // [kwave][tile][lane] partial xproj sums
  int tid = threadIdx.x;
  int m0 = blockIdx.x * CBT;
  // ---- phase A: causal depthwise conv4 + bias + SiLU (rolling 4-row register window) ----
  {
    int d = tid * 4;
    float w[4][4], bias[4];
    #pragma unroll
    for (int c = 0; c < 4; ++c){
      #pragma unroll
      for (int j = 0; j < 4; ++j) w[c][j] = cw[(d + c)*4 + j];
      bias[c] = cb[d + c];
    }
    bf16x4 zero4; zero4[0] = (__bf16)0.f; zero4[1] = (__bf16)0.f; zero4[2] = (__bf16)0.f; zero4[3] = (__bf16)0.f;
    bf16x4 rm3 = (m0 >= 3) ? *(const bf16x4*)(xz16 + (size_t)(m0-3)*2048 + d) : zero4;
    bf16x4 rm2 = (m0 >= 2) ? *(const bf16x4*)(xz16 + (size_t)(m0-2)*2048 + d) : zero4;
    bf16x4 rm1 = (m0 >= 1) ? *(const bf16x4*)(xz16 + (size_t)(m0-1)*2048 + d) : zero4;
    for (int ti = 0; ti < CBT; ++ti){
      int m = m0 + ti;
      bf16x4 cur = *(const bf16x4*)(xz16 + (size_t)m*2048 + d);
      float acc[4] = {0.f, 0.f, 0.f, 0.f};
      if (m < M_VALID){
        int b = m / L_WIN;
        int l = m - b*L_WIN;
        #pragma unroll
        for (int c = 0; c < 4; ++c) acc[c] = fmaf((float)cur[c], w[c][3], bias[c]);
        if (l >= 1){
          #pragma unroll
          for (int c = 0; c < 4; ++c) acc[c] = fmaf((float)rm1[c], w[c][2], acc[c]);
        }
        if (l >= 2){
          #pragma unroll
          for (int c = 0; c < 4; ++c) acc[c] = fmaf((float)rm2[c], w[c][1], acc[c]);
        }
        if (l >= 3){
          #pragma unroll
          for (int c = 0; c < 4; ++c) acc[c] = fmaf((float)rm3[c], w[c][0], acc[c]);
        }
        #pragma unroll
        for (int c = 0; c < 4; ++c) acc[c] = acc[c] * sigmoidf_(acc[c]);
      }
      bf16x4 o;
      #pragma unroll
      for (int c = 0; c < 4; ++c) o[c] = (__bf16)acc[c];
      *(bf16x4*)(u16 + (size_t)m*DI + d) = o;
      *(bf16x4*)(&su[ti][d]) = o;
      rm3 = rm2; rm2 = rm1; rm1 = cur;
    }
  }
  __syncthreads();
  // ---- phase B: xproj, CBT tokens x 48 outputs, K=1024 split across 4 waves ----
  {
    int lane = tid & 63, wv = tid >> 6;
    int row = lane & 15, kq = lane >> 4;
    int kbase = wv * 256;
    f32x4 acc0 = {0,0,0,0}, acc1 = {0,0,0,0}, acc2 = {0,0,0,0};
    const __bf16* B0 = wxp + (size_t)(row)*1024      + kbase + kq*8;
    const __bf16* B1 = wxp + (size_t)(16 + row)*1024 + kbase + kq*8;
    const __bf16* B2 = wxp + (size_t)(32 + row)*1024 + kbase + kq*8;
    #pragma unroll
    for (int k = 0; k < 256; k += 32){
      bf16x8 a = *(const bf16x8*)(&su[row][kbase + k + kq*8]);
      acc0 = __builtin_amdgcn_mfma_f32_16x16x32_bf16(a, *(const bf16x8*)(B0 + k), acc0, 0, 0, 0);
      acc1 = __builtin_amdgcn_mfma_f32_16x16x32_bf16(a, *(const bf16x8*)(B1 + k), acc1, 0, 0, 0);
      acc2 = __builtin_amdgcn_mfma_f32_16x16x32_bf16(a, *(const bf16x8*)(B2 + k), acc2, 0, 0, 0);
    }
    spart[wv][0][lane] = acc0;
    spart[wv][1][lane] = acc1;
    spart[wv][2][lane] = acc2;
  }
  __syncthreads();
  // ---- reduce partials, write xdbl + sdt (only valid tokens) ----
  if (tid < 192){
    int tno = tid >> 6, lane = tid & 63;
    int row = lane & 15, kq = lane >> 4;
    f32x4 sum = spart[0][tno][lane];
    sum += spart[1][tno][lane];
    sum += spart[2][tno][lane];
    sum += spart[3][tno][lane];
    #pragma unroll
    for (int i = 0; i < 4; ++i){
      int tok = kq*4 + i;
      if (tok < CBT){
        xdbl[(size_t)(m0 + tok)*48 + tno*16 + row] = sum[i];
        if (tno == 0) sdt[tok][row] = sum[i];
      }
    }
  }
  __syncthreads();
  // ---- phase C: dt_proj (K=16) + softplus -> delta16 ----
  {
    int d0 = tid * 4;
    float w[4][16], bias[4];
    #pragma unroll
    for (int c = 0; c < 4; ++c){
      #pragma unroll
      for (int q = 0; q < 16; ++q) w[c][q] = dtw[(d0 + c)*16 + q];
      bias[c] = dtb[d0 + c];
    }
    for (int t = 0; t < CBT; ++t){
      float acc[4] = {bias[0], bias[1], bias[2], bias[3]};
      #pragma unroll
      for (int r = 0; r < 16; ++r){
        float dv = sdt[t][r];
        #pragma unroll
        for (int c = 0; c < 4; ++c) acc[c] = fmaf(dv, w[c][r], acc[c]);
      }
      bf16x4 o;
      #pragma unroll
      for (int c = 0; c < 4; ++c) o[c] = (__bf16)softplusf_(acc[c]);
      *(bf16x4*)(delta16 + (size_t)(m0 + t)*DI + d0) = o;
    }
  }
}

// ================= chunked two-phase selective scan =================
// r10: token-PAIR processing — sdd[c][t..t+1] in one ds_read_b128; sB/sBC
// transposed to [n][t] so B/C pairs also load as one b64/b128. Halves the
// LDS-read instruction count in the 64-iteration serial loops.
__global__ __launch_bounds__(256) void scan_part1_kernel(
  const __bf16* __restrict__ u16, const __bf16* __restrict__ delta16,
  const float* __restrict__ xdbl, const float* __restrict__ Alog, float2* __restrict__ Pq)
{
  int bid = blockIdx.x;
  int s = bid & 15, dtile = (bid >> 4) & 63, b = bid >> 10;
  if (s == 15) return;   // last segment's (P,h) is never read
  int d0 = dtile << 4;
  int tid = threadIdx.x;
  int c = tid >> 4, n = tid & 15;
  float A2 = -__expf(Alog[(d0 + c)*16 + n]) * LOG2E;
  __shared__ float2 sdd[16][SEG+2];   // [d][t] (dlt, dlt*u)
  __shared__ float  sBt[16][SEG+2];   // [n][t] B  (transposed for paired reads)
  int t0 = s*SEG;
  int nt = L_WIN - t0; if (nt > SEG) nt = SEG;
  size_t base_m = (size_t)b*L_WIN + t0;
  if (tid < 128){
    int row = tid >> 1, half = tid & 1;
    bf16x8 dl8, u8;
    if (row < nt){
      size_t m = base_m + row;
      dl8 = *(const bf16x8*)(delta16 + m*DI + d0 + half*8);
      u8  = *(const bf16x8*)(u16    + m*DI + d0 + half*8);
    } else {
      #pragma unroll
      for (int j = 0; j < 8; ++j){ dl8[j] = (__bf16)0.f; u8[j] = (__bf16)0.f; }
    }
    #pragma unroll
    for (int j = 0; j < 8; ++j){
      float dlt = (float)dl8[j];
      sdd[half*8 + j][row] = make_float2(dlt, dlt * (float)u8[j]);
    }
  }
  {
    int row = tid & 63, q = tid >> 6;
    f32x4 B4 = {0,0,0,0};
    if (row < nt) B4 = *(const f32x4*)(xdbl + (base_m + row)*48 + 16 + q*4);
    #pragma unroll
    for (int j = 0; j < 4; ++j) sBt[q*4 + j][row] = B4[j];
  }
  __syncthreads();
  float h = 0.f, sd = 0.f;
  #pragma unroll 4
  for (int t = 0; t < SEG; t += 2){
    f32x4 dp  = *(const f32x4*)&sdd[c][t];     // (dlt0,du0,dlt1,du1)
    float2 b2 = *(const float2*)&sBt[n][t];    // (B0,B1)
    float dA0 = exp2f(dp[0] * A2);
    h = fmaf(dA0, h, dp[1] * b2.x);
    sd += dp[0];
    float dA1 = exp2f(dp[2] * A2);
    h = fmaf(dA1, h, dp[3] * b2.y);
    sd += dp[2];
  }
  float P = exp2f(sd * A2);
  Pq[(((size_t)b*NSEG + s) << 14) + (dtile << 8) + tid] = make_float2(P, h);
}

__global__ __launch_bounds__(256) void scan_part2_kernel(
  const __bf16* __restrict__ u16, const __bf16* __restrict__ delta16,
  const float* __restrict__ xdbl, const __bf16* __restrict__ xz16,
  const float* __restrict__ Alog, const float* __restrict__ Dp,
  const float2* __restrict__ Pq, __bf16* __restrict__ y16)
{
  int bid = blockIdx.x;
  int s = bid & 15, dtile = (bid >> 4) & 63, b = bid >> 10;
  int d0 = dtile << 4;
  int tid = threadIdx.x;
  int c = tid >> 4, n = tid & 15;
  float A2 = -__expf(Alog[(d0 + c)*16 + n]) * LOG2E;
  __shared__ float2 sdd [16][SEG+2];  // [d][t] (dlt, dlt*u); becomes (y_lo,y_hi)
  __shared__ float2 sBCt[16][SEG+2];  // [n][t] (B, C)  (transposed for paired reads)
  __shared__ float  sD[16];
  if (tid < 16) sD[tid] = Dp[d0 + tid];
  int t0 = s*SEG;
  int nt = L_WIN - t0; if (nt > SEG) nt = SEG;
  size_t base_m = (size_t)b*L_WIN + t0;
  // ---- vectorized staging (issues before the prefix chain) ----
  if (tid < 128){
    int row = tid >> 1, half = tid & 1;
    bf16x8 dl8, u8;
    if (row < nt){
      size_t m = base_m + row;
      dl8 = *(const bf16x8*)(delta16 + m*DI + d0 + half*8);
      u8  = *(const bf16x8*)(u16    + m*DI + d0 + half*8);
    } else {
      #pragma unroll
      for (int j = 0; j < 8; ++j){ dl8[j] = (__bf16)0.f; u8[j] = (__bf16)0.f; }
    }
    #pragma unroll
    for (int j = 0; j < 8; ++j){
      float dlt = (float)dl8[j];
      sdd[half*8 + j][row] = make_float2(dlt, dlt * (float)u8[j]);
    }
  }
  {
    int row = tid & 63, q = tid >> 6;
    f32x4 B4 = {0,0,0,0}, C4 = {0,0,0,0};
    if (row < nt){
      size_t m = base_m + row;
      B4 = *(const f32x4*)(xdbl + m*48 + 16 + q*4);
      C4 = *(const f32x4*)(xdbl + m*48 + 32 + q*4);
    }
    #pragma unroll
    for (int j = 0; j < 4; ++j) sBCt[q*4 + j][row] = make_float2(B4[j], C4[j]);
  }
  // ---- batched prefix over earlier segments' (P,q): 8 loads in flight ----
  float h = 0.f;
  {
    size_t pqbase = (((size_t)b*NSEG) << 14) + (dtile << 8) + tid;
    for (int s0 = 0; s0 < 15; s0 += 8){
      if (s0 >= s) break;               // wave-uniform
      float2 r[8];
      #pragma unroll
      for (int j = 0; j < 8; ++j)
        r[j] = Pq[pqbase + ((size_t)(s0 + j) << 14)];
      #pragma unroll
      for (int j = 0; j < 8; ++j)
        if (s0 + j < s) h = fmaf(r[j].x, h, r[j].y);
    }
  }
  __syncthreads();
  // ---- serial chain (token pairs) + 3-step DPP reduce; halves into sdd[c][t].x/.y ----
  bool wl = ((n & 7) == 0);
  int wslot = n >> 3;                   // 0 -> .x, 1 -> .y
  #pragma unroll 4
  for (int t = 0; t < SEG; t += 2){
    f32x4 dp = *(const f32x4*)&sdd[c][t];     // (dlt0,du0,dlt1,du1) — read before writes below
    f32x4 bc = *(const f32x4*)&sBCt[n][t];    // (B0,C0,B1,C1)
    float dA0 = exp2f(dp[0] * A2);
    h = fmaf(dA0, h, dp[1] * bc[0]);
    float pp0 = h * bc[1];
    pp0 = dpp_add<0xB1>(pp0);
    pp0 = dpp_add<0x4E>(pp0);
    pp0 = dpp_add<0x141>(pp0);
    if (wl) ((float*)&sdd[c][t])[wslot] = pp0;      // wave-private row
    float dA1 = exp2f(dp[2] * A2);
    h = fmaf(dA1, h, dp[3] * bc[2]);
    float pp1 = h * bc[3];
    pp1 = dpp_add<0xB1>(pp1);
    pp1 = dpp_add<0x4E>(pp1);
    pp1 = dpp_add<0x141>(pp1);
    if (wl) ((float*)&sdd[c][t+1])[wslot] = pp1;
  }
  __syncthreads();
  // ---- vectorized epilogue: threads 0..127, one half-row each ----
  if (tid < 128){
    int tt = tid >> 1, half = tid & 1;
    if (tt < nt){
      size_t m = base_m + tt;
      bf16x8 z8 = *(const bf16x8*)(xz16 + m*2048 + 1024 + d0 + half*8);
      bf16x8 u8 = *(const bf16x8*)(u16 + m*DI + d0 + half*8);
      bf16x8 o;
      #pragma unroll
      for (int j = 0; j < 8; ++j){
        int dd = half*8 + j;
        float2 yh = sdd[dd][tt];
        float zv = (float)z8[j];
        float yv = ((yh.x + yh.y) + (float)u8[j] * sD[dd]) * (zv * sigmoidf_(zv));
        o[j] = (__bf16)yv;
      }
      *(bf16x8*)(y16 + m*DI + d0 + half*8) = o;
    }
  }
}

// ---------------- overlap-add fold + passthrough ----------------
__global__ __launch_bounds__(256) void fold_kernel(const float* __restrict__ x, const float* __restrict__ r,
                                                   float* __restrict__ out){
  int i = blockIdx.x*256 + threadIdx.x;
  int b = i >> 17;
  int t = i & (TLEN - 1);
  float acc = x[i];
  int l1 = t >> 7;
  int j  = t & 127;
  if (l1 < L_WIN) acc += r[((size_t)b*L_WIN + l1)*DIMC + j] * ((float)j * (1.f/127.f));
  if (l1 >= 1)    acc += r[((size_t)b*L_WIN + l1 - 1)*DIMC + j + 128] * ((float)(127 - j) * (1.f/127.f));
  out[i] = acc;
}

extern "C" void kernel_launch(void* const* d_in, const int* in_sizes, int n_in,
                              void* d_out, int out_size, void* d_ws, size_t ws_size,
                              hipStream_t stream)
{
  (void)in_sizes; (void)n_in; (void)out_size; (void)ws_size;
  const float* x      = (const float*)d_in[0];
  const float* in_w   = (const float*)d_in[1];
  const float* conv_w = (const float*)d_in[2];
  const float* conv_b = (const float*)d_in[3];
  const float* xp_w   = (const float*)d_in[4];
  const float* dt_w   = (const float*)d_in[5];
  const float* dt_b   = (const float*)d_in[6];
  const float* A_log  = (const float*)d_in[7];
  const float* Dp     = (const float*)d_in[8];
  const float* out_w  = (const float*)d_in[9];
  const float* norm_w = (const float*)d_in[10];
  float* out = (float*)d_out;

  // workspace layout (~56 MB; ws is 256 MiB)
  char* p = (char*)d_ws;
  auto alloc = [&](size_t bytes)->void*{ void* r = (void*)p; p += (bytes + 255) & ~(size_t)255; return r; };
  float*  res    = (float*) alloc((size_t)M_PAD*DIMC*4);        // 4 MB
  __bf16* hn16   = (__bf16*)alloc((size_t)M_PAD*DIMC*2);        // 2 MB
  __bf16* xz16   = (__bf16*)alloc((size_t)M_PAD*2048*2);        // 16 MB
  __bf16* u16    = (__bf16*)alloc((size_t)M_PAD*DI*2);          // 8 MB
  float*  xdbl   = (float*) alloc((size_t)M_PAD*48*4);          // 0.75 MB
  __bf16* delta16= (__bf16*)alloc((size_t)M_PAD*DI*2);          // 8 MB
  __bf16* y16    = (__bf16*)alloc((size_t)M_PAD*DI*2);          // 8 MB
  float2* Pq     = (float2*)alloc((size_t)4*NSEG*16384*8);      // 8 MB
  float*  rowsum = (float*) alloc((size_t)M_PAD*4);             // 16 KB
  __bf16* w_in16 = (__bf16*)alloc((size_t)2*2048*256*2);        // 2 MB
  __bf16* w_xp16 = (__bf16*)alloc((size_t)2*48*1024*2);         // 0.19 MB
  __bf16* w_out16= (__bf16*)alloc((size_t)2*256*1024*2);        // 1 MB

  init_kernel<<<M_PAD + 512, 256, 0, stream>>>(x, res, hn16, norm_w, rowsum,
                                               in_w, w_in16, 2*2048*256,
                                               xp_w, w_xp16, 2*48*1024,
                                               out_w, w_out16, 2*256*1024);

  for (int i = 0; i < 2; ++i){
    // in_proj: M=4096 N=2048 K=256; 128x64 tile -> 1024 blocks = 4/CU
    if (i == 0)
      gemm_tiled_kernel<4, 2, __bf16><<<dim3(32, 32), 256, 0, stream>>>(hn16, w_in16, xz16, nullptr, nullptr, 256, 2048);
    else
      gemm_rms2_kernel<<<dim3(32, 32), 256, 0, stream>>>(res, w_in16 + 524288, rowsum, norm_w + 256, xz16, 2048);
    conv_xproj_dt_kernel<<<M_PAD/CBT, 256, 0, stream>>>(xz16, conv_w + i*4096, conv_b + i*1024,
                                                        w_xp16 + (size_t)i*49152, dt_w + i*16384, dt_b + i*1024,
                                                        u16, xdbl, delta16);
    scan_part1_kernel<<<4096, 256, 0, stream>>>(u16, delta16, xdbl, A_log + i*16384, Pq);
    scan_part2_kernel<<<4096, 256, 0, stream>>>(u16, delta16, xdbl, xz16, A_log + i*16384, Dp + i*1024,
                                                Pq, y16);
    // out_proj: M=4096 N=256 K=1024; 32x32 tile -> 1024 blocks = 4/CU.
    // Layer 0 also accumulates rowsum (feeds layer-1 fused rms).
    gemm_tiled_kernel<1, 1, float><<<dim3(128, 8), 256, 0, stream>>>(y16, w_out16 + (size_t)i*262144, res, res,
                                                                     (i == 0) ? rowsum : nullptr, 1024, 256);
  }
  fold_kernel<<<TLEN*4/256, 256, 0, stream>>>(x, res, out);
}